// Round 6
// baseline (1524.677 us; speedup 1.0000x reference)
//
#include <hip/hip_runtime.h>
#include <math.h>

#define T 2048
#define H 4096
#define NQ 32
#define NKV 8
#define HD 128
#define VD 96
#define WIN 1024
#define NE 8
#define FF 1408
#define TOPK 2

typedef __bf16 bf16x8 __attribute__((ext_vector_type(8)));
typedef unsigned short u16x8 __attribute__((ext_vector_type(8)));
typedef float f32x4 __attribute__((ext_vector_type(4)));
typedef unsigned short ushort_t;

__device__ __forceinline__ unsigned short f2bf(float f) {
  union { float f; unsigned u; } v; v.f = f;
  unsigned r = v.u + 0x7fffu + ((v.u >> 16) & 1u);
  return (unsigned short)(r >> 16);
}
__device__ __forceinline__ float bf2f(unsigned short h) {
  union { unsigned u; float f; } v; v.u = ((unsigned)h) << 16;
  return v.f;
}
__device__ __forceinline__ f32x4 mfma16(bf16x8 a, bf16x8 b, f32x4 c) {
  return __builtin_amdgcn_mfma_f32_16x16x32_bf16(a, b, c, 0, 0, 0);
}
__device__ __forceinline__ f32x4 fzero4() { f32x4 z = {0.f, 0.f, 0.f, 0.f}; return z; }

__device__ __forceinline__ void gl16(const void* g, void* l) {
  __builtin_amdgcn_global_load_lds(
      (const __attribute__((address_space(1))) void*)g,
      (__attribute__((address_space(3))) void*)l, 16, 0, 0);
}

// ---------------------------------------------------------------------------
// Phased double-buffered GEMM (counted-vmcnt pipeline, T2+T3+T4+T5).
// A bf16 [M][K], B bf16 BT [N][K]. BM=BN=128, BK=64, 256 threads (4 waves,
// 64x64 per wave), LDS 64KB -> 2 blocks/CU. 4 phases / 2 K-tiles; vmcnt(4)
// at phases 2,4 only. LDS XOR-swizzle: k-chunk ^= (row&3) (stage-source
// pre-swizzled + swizzled reads).
// ---------------------------------------------------------------------------
template<int GATHER, int EOFF, int OUTBF, int RES>
__global__ __launch_bounds__(256) void gemm8p(
    const ushort_t* __restrict__ A, int lda,
    const ushort_t* __restrict__ B, long long strideBe,
    void* __restrict__ Cp, int ldc,
    const float* __restrict__ res,
    const int* __restrict__ row_idx, const int* __restrict__ e_off,
    int M, int K)
{
  __shared__ __align__(16) ushort_t lds[32768];  // 64 KB

  int rowbase = 0, Mloc = M;
  if (EOFF) {
    int e = blockIdx.z;
    rowbase = e_off[e];
    Mloc = e_off[e + 1] - rowbase;
    B += strideBe * (long long)e;
  }
  int mtile = blockIdx.y * 128;
  if (mtile >= Mloc) return;
  int n0 = blockIdx.x * 128;

  int tid = threadIdx.x;
  int lane = tid & 63;
  int wave = tid >> 6;          // 0..3
  int wm = wave >> 1;           // 0..1
  int wn = wave & 1;            // 0..1
  int g  = lane >> 4;           // 0..3
  int cc = lane & 15;
  int gx = g ^ (cc & 3);

  // LDS read offsets (ushort units). A region [0,16384), B [16384,32768).
  int aoff = (wm * 64 + cc) * 32 + gx * 8;
  int boff = 16384 + (wn * 64 + cc) * 32 + gx * 8;

  // staging source pointers (pre-swizzled k)
  int r2 = tid >> 2;                       // 0..63
  int kx = ((tid & 3) ^ (r2 & 3)) * 8;     // element offset, bits swizzled
  const ushort_t *pa0, *pa1;
  {
    long long ar0, ar1;
    if (EOFF) {
      int l0 = mtile + r2;       if (l0 > Mloc - 1) l0 = Mloc - 1;
      int l1 = mtile + r2 + 64;  if (l1 > Mloc - 1) l1 = Mloc - 1;
      if (GATHER) { ar0 = row_idx[rowbase + l0]; ar1 = row_idx[rowbase + l1]; }
      else        { ar0 = rowbase + l0;          ar1 = rowbase + l1; }
    } else {
      ar0 = mtile + r2; ar1 = mtile + r2 + 64;
    }
    pa0 = A + ar0 * (long long)lda + kx;
    pa1 = A + ar1 * (long long)lda + kx;
  }
  const ushort_t* pb0 = B + (size_t)(n0 + r2) * K + kx;
  const ushort_t* pb1 = B + (size_t)(n0 + r2 + 64) * K + kx;

#define SA(slot, ks, kt) do {                                                  \
    gl16(pa0 + (size_t)(kt) * 64 + (ks) * 32,                                  \
         &lds[(slot) * 8192 + (ks) * 4096 + tid * 8]);                         \
    gl16(pa1 + (size_t)(kt) * 64 + (ks) * 32,                                  \
         &lds[(slot) * 8192 + (ks) * 4096 + tid * 8 + 2048]); } while (0)
#define SB(slot, ks, kt) do {                                                  \
    gl16(pb0 + (size_t)(kt) * 64 + (ks) * 32,                                  \
         &lds[16384 + (slot) * 8192 + (ks) * 4096 + tid * 8]);                 \
    gl16(pb1 + (size_t)(kt) * 64 + (ks) * 32,                                  \
         &lds[16384 + (slot) * 8192 + (ks) * 4096 + tid * 8 + 2048]); } while (0)

  f32x4 acc[4][4];
#pragma unroll
  for (int m = 0; m < 4; ++m)
#pragma unroll
    for (int n = 0; n < 4; ++n) acc[m][n] = fzero4();

  int NKT = K >> 6;
  int NI = NKT >> 1;

  // prologue: t0 fully (both ks), t1 ks0
  SA(0, 0, 0); SB(0, 0, 0);
  SA(0, 1, 0); SB(0, 1, 0);
  SA(1, 0, 1); SB(1, 0, 1);
  asm volatile("s_waitcnt vmcnt(4)" ::: "memory");
  __builtin_amdgcn_s_barrier();
  asm volatile("" ::: "memory");

#define PH(slot, ks, STAGEOP, WAITOP)                                          \
  {                                                                            \
    bf16x8 a_[4], b_[4];                                                       \
    _Pragma("unroll") for (int mm = 0; mm < 4; ++mm)                           \
      a_[mm] = *(const bf16x8*)&lds[(slot) * 8192 + (ks) * 4096 + aoff + mm * 512]; \
    _Pragma("unroll") for (int nn = 0; nn < 4; ++nn)                           \
      b_[nn] = *(const bf16x8*)&lds[(slot) * 8192 + (ks) * 4096 + boff + nn * 512]; \
    STAGEOP;                                                                   \
    WAITOP;                                                                    \
    asm volatile("" ::: "memory");                                             \
    __builtin_amdgcn_s_barrier();                                              \
    asm volatile("" ::: "memory");                                             \
    __builtin_amdgcn_s_setprio(1);                                             \
    _Pragma("unroll") for (int mm = 0; mm < 4; ++mm)                           \
      _Pragma("unroll") for (int nn = 0; nn < 4; ++nn)                         \
        acc[mm][nn] = mfma16(a_[mm], b_[nn], acc[mm][nn]);                     \
    __builtin_amdgcn_s_setprio(0);                                             \
    asm volatile("s_waitcnt lgkmcnt(0)" ::: "memory");                         \
    __builtin_amdgcn_s_barrier();                                              \
    asm volatile("" ::: "memory");                                             \
  }

  for (int i = 0; i < NI; ++i) {
    int t1 = 2 * i + 1;
    int t2 = 2 * i + 2; if (t2 > NKT - 1) t2 = NKT - 1;
    int t3 = 2 * i + 3; if (t3 > NKT - 1) t3 = NKT - 1;
    PH(0, 0, SA(1, 1, t1); SB(1, 1, t1), )
    PH(0, 1, SA(0, 0, t2); SB(0, 0, t2),
       asm volatile("s_waitcnt vmcnt(4)" ::: "memory"))
    PH(1, 0, SA(0, 1, t2); SB(0, 1, t2), )
    PH(1, 1, SA(1, 0, t3); SB(1, 0, t3),
       asm volatile("s_waitcnt vmcnt(4)" ::: "memory"))
  }
#undef PH
#undef SA
#undef SB

  int lr4 = (lane >> 4) * 4;
#pragma unroll
  for (int m = 0; m < 4; ++m) {
    int rowl = mtile + wm * 64 + m * 16 + lr4;
#pragma unroll
    for (int n = 0; n < 4; ++n) {
      int col = n0 + wn * 64 + n * 16 + cc;
#pragma unroll
      for (int r = 0; r < 4; ++r) {
        int grow = rowl + r;
        if (!EOFF || grow < Mloc) {
          size_t off = (size_t)(rowbase + grow) * ldc + col;
          float vv = acc[m][n][r];
          if (OUTBF) {
            ((ushort_t*)Cp)[off] = f2bf(vv);
          } else {
            if (RES) vv += res[off];
            ((float*)Cp)[off] = vv;
          }
        }
      }
    }
  }
}

// ---------------------------------------------------------------------------
// Transpose + f32->bf16: src [R][C] f32 -> dst rows [dro+c][r] (hi only).
// ---------------------------------------------------------------------------
template<int SPLITOUT>
__global__ __launch_bounds__(256) void tconv_kernel(
    const float* __restrict__ src, int ldsrc,
    ushort_t* __restrict__ dh, ushort_t* __restrict__ dl,
    int lddst, int dro, long long sE, long long dE)
{
  __shared__ float tile[64][65];
  int e = blockIdx.z;
  src += sE * (long long)e;
  dh += dE * (long long)e;
  if (SPLITOUT) dl += dE * (long long)e;
  int c0 = blockIdx.x * 64;
  int r0 = blockIdx.y * 64;
  int tid = threadIdx.x;
#pragma unroll
  for (int i = 0; i < 4; ++i) {
    int idx = tid + i * 256;
    int r = idx >> 4, c4 = (idx & 15) << 2;
    float4 v = *(const float4*)&src[(size_t)(r0 + r) * ldsrc + c0 + c4];
    tile[r][c4 + 0] = v.x; tile[r][c4 + 1] = v.y;
    tile[r][c4 + 2] = v.z; tile[r][c4 + 3] = v.w;
  }
  __syncthreads();
#pragma unroll
  for (int i = 0; i < 2; ++i) {
    int idx = tid + i * 256;
    int c = idx >> 3, r8 = (idx & 7) << 3;
    u16x8 hv, lv;
#pragma unroll
    for (int j = 0; j < 8; ++j) {
      float f = tile[r8 + j][c];
      unsigned short hh = f2bf(f);
      hv[j] = hh;
      if (SPLITOUT) lv[j] = f2bf(f - bf2f(hh));
    }
    size_t o = (size_t)(dro + c0 + c) * lddst + r0 + r8;
    *(u16x8*)&dh[o] = hv;
    if (SPLITOUT) *(u16x8*)&dl[o] = lv;
  }
}

// ---------------------------------------------------------------------------
// Transpose + convert into K-cat layout: hi at kh1,kh2; lo at klo.
// ---------------------------------------------------------------------------
__global__ __launch_bounds__(256) void tconv_cat_kernel(
    const float* __restrict__ src, int ldsrc,
    ushort_t* __restrict__ dst, int lddst, int dro,
    int kh1, int kh2, int klo)
{
  __shared__ float tile[64][65];
  int c0 = blockIdx.x * 64;
  int r0 = blockIdx.y * 64;
  int tid = threadIdx.x;
#pragma unroll
  for (int i = 0; i < 4; ++i) {
    int idx = tid + i * 256;
    int r = idx >> 4, c4 = (idx & 15) << 2;
    float4 v = *(const float4*)&src[(size_t)(r0 + r) * ldsrc + c0 + c4];
    tile[r][c4 + 0] = v.x; tile[r][c4 + 1] = v.y;
    tile[r][c4 + 2] = v.z; tile[r][c4 + 3] = v.w;
  }
  __syncthreads();
#pragma unroll
  for (int i = 0; i < 2; ++i) {
    int idx = tid + i * 256;
    int c = idx >> 3, r8 = (idx & 7) << 3;
    u16x8 hv, lv;
#pragma unroll
    for (int j = 0; j < 8; ++j) {
      float f = tile[r8 + j][c];
      unsigned short hh = f2bf(f);
      hv[j] = hh;
      lv[j] = f2bf(f - bf2f(hh));
    }
    size_t o = (size_t)(dro + c0 + c) * lddst + r0 + r8;
    *(u16x8*)&dst[o + kh1] = hv;
    *(u16x8*)&dst[o + kh2] = hv;
    *(u16x8*)&dst[o + klo] = lv;
  }
}

// ---------------------------------------------------------------------------
// RMSNorm 1: f32 in -> x1cat bf16 [T][12288] = [hi | lo | hi].
// ---------------------------------------------------------------------------
__global__ __launch_bounds__(256) void rmsnorm_cat_kernel(const float* __restrict__ in,
    const float* __restrict__ w, ushort_t* __restrict__ oc)
{
  int t = blockIdx.x;
  int tid = threadIdx.x;
  const float4* rp = (const float4*)(in + (size_t)t * H);
  const float4* wp = (const float4*)w;
  float4 vv[4];
  float ss = 0.f;
#pragma unroll
  for (int i = 0; i < 4; ++i) {
    vv[i] = rp[tid + i * 256];
    ss += vv[i].x * vv[i].x + vv[i].y * vv[i].y + vv[i].z * vv[i].z + vv[i].w * vv[i].w;
  }
#pragma unroll
  for (int off = 32; off > 0; off >>= 1) ss += __shfl_xor(ss, off);
  __shared__ float red[4];
  if ((tid & 63) == 0) red[tid >> 6] = ss;
  __syncthreads();
  float tot = red[0] + red[1] + red[2] + red[3];
  float rs = rsqrtf(tot * (1.f / H) + 1e-6f);
#pragma unroll
  for (int i = 0; i < 4; ++i) {
    float4 x = vv[i];
    float4 ww = wp[tid + i * 256];
    float y0 = x.x * rs * ww.x, y1 = x.y * rs * ww.y;
    float y2 = x.z * rs * ww.z, y3 = x.w * rs * ww.w;
    ushort4 hh, ll;
    hh.x = f2bf(y0); hh.y = f2bf(y1); hh.z = f2bf(y2); hh.w = f2bf(y3);
    ll.x = f2bf(y0 - bf2f(hh.x)); ll.y = f2bf(y1 - bf2f(hh.y));
    ll.z = f2bf(y2 - bf2f(hh.z)); ll.w = f2bf(y3 - bf2f(hh.w));
    size_t base = (size_t)t * 12288 + (tid + i * 256) * 4;
    *(ushort4*)&oc[base] = hh;
    *(ushort4*)&oc[base + 4096] = ll;
    *(ushort4*)&oc[base + 8192] = hh;
  }
}

// ---------------------------------------------------------------------------
// RMSNorm 2: f32 in -> f32 out (router) + bf16 hi out (MoE A operand).
// ---------------------------------------------------------------------------
__global__ __launch_bounds__(256) void rmsnorm_fh_kernel(const float* __restrict__ in,
    const float* __restrict__ w, float* __restrict__ of, ushort_t* __restrict__ oh)
{
  int t = blockIdx.x;
  int tid = threadIdx.x;
  const float4* rp = (const float4*)(in + (size_t)t * H);
  const float4* wp = (const float4*)w;
  float4 vv[4];
  float ss = 0.f;
#pragma unroll
  for (int i = 0; i < 4; ++i) {
    vv[i] = rp[tid + i * 256];
    ss += vv[i].x * vv[i].x + vv[i].y * vv[i].y + vv[i].z * vv[i].z + vv[i].w * vv[i].w;
  }
#pragma unroll
  for (int off = 32; off > 0; off >>= 1) ss += __shfl_xor(ss, off);
  __shared__ float red[4];
  if ((tid & 63) == 0) red[tid >> 6] = ss;
  __syncthreads();
  float tot = red[0] + red[1] + red[2] + red[3];
  float rs = rsqrtf(tot * (1.f / H) + 1e-6f);
#pragma unroll
  for (int i = 0; i < 4; ++i) {
    float4 x = vv[i];
    float4 ww = wp[tid + i * 256];
    float4 o;
    o.x = x.x * rs * ww.x; o.y = x.y * rs * ww.y;
    o.z = x.z * rs * ww.z; o.w = x.w * rs * ww.w;
    *(float4*)&of[(size_t)t * H + (tid + i * 256) * 4] = o;
    ushort4 hh;
    hh.x = f2bf(o.x); hh.y = f2bf(o.y); hh.z = f2bf(o.z); hh.w = f2bf(o.w);
    *(ushort4*)&oh[(size_t)t * H + (tid + i * 256) * 4] = hh;
  }
}

// ---------------------------------------------------------------------------
// RoPE + pack from fused qkv f32 [T][5888] -> bf16 hi/lo q/k/v buffers.
// ---------------------------------------------------------------------------
__global__ __launch_bounds__(256) void rope_pack_kernel(const int* __restrict__ pos,
    const float* __restrict__ qkv,
    ushort_t* __restrict__ qh, ushort_t* __restrict__ ql,
    ushort_t* __restrict__ kh, ushort_t* __restrict__ kl,
    ushort_t* __restrict__ vh, ushort_t* __restrict__ vl)
{
  int t = blockIdx.x;
  float p = (float)pos[t];
  int tid = threadIdx.x;
  const float* row = qkv + (size_t)t * 5888;
  for (int idx = tid; idx < (NQ + NKV) * 64; idx += 256) {
    int col; ushort_t *dh, *dl; size_t dbase; int d;
    if (idx < NQ * 64) {
      int hh = idx >> 6; d = idx & 63;
      col = hh * HD + d;
      dbase = (size_t)t * (NQ * HD) + hh * HD;
      dh = qh; dl = ql;
    } else {
      int j = idx - NQ * 64;
      int hh = j >> 6; d = j & 63;
      col = 4096 + hh * HD + d;
      dbase = (size_t)t * (NKV * HD) + hh * HD;
      dh = kh; dl = kl;
    }
    float inv = exp2f(-19.931568569324174f * (float)(2 * d) * (1.0f / 128.0f));
    float ang = p * inv;
    float sn = sinf(ang), cs = cosf(ang);
    float x1 = row[col], x2 = row[col + 64];
    float o1 = x1 * cs - x2 * sn;
    float o2 = x2 * cs + x1 * sn;
    unsigned short h1 = f2bf(o1), h2 = f2bf(o2);
    dh[dbase + d] = h1; dl[dbase + d] = f2bf(o1 - bf2f(h1));
    dh[dbase + d + 64] = h2; dl[dbase + d + 64] = f2bf(o2 - bf2f(h2));
  }
  for (int idx = tid; idx < NKV * VD; idx += 256) {
    float v = row[5120 + idx];
    size_t o = (size_t)t * (NKV * VD) + idx;
    unsigned short hh = f2bf(v);
    vh[o] = hh; vl[o] = f2bf(v - bf2f(hh));
  }
}

// ---------------------------------------------------------------------------
// Flash attention (split-bf16, window + sink). Output -> aocat [T][9216]
// = [hi | lo | hi] for the K-cat WO GEMM.
// ---------------------------------------------------------------------------
__global__ __launch_bounds__(256) void attn_kernel(
    const ushort_t* __restrict__ qh, const ushort_t* __restrict__ ql,
    const ushort_t* __restrict__ kh, const ushort_t* __restrict__ kl,
    const ushort_t* __restrict__ vhp, const ushort_t* __restrict__ vlp,
    const float* __restrict__ sink, const int* __restrict__ pos,
    ushort_t* __restrict__ aocat)
{
  __shared__ __align__(16) ushort_t Qs[2][64][136];
  __shared__ __align__(16) ushort_t Ks[2][32][136];
  __shared__ __align__(16) ushort_t Vt[2][96][40];
  __shared__ __align__(16) ushort_t Ps[2][4][16][40];
  __shared__ int posq[64];
  __shared__ int posk[32];

  const float SCALE = 0.08838834764831843f;
  int qs = blockIdx.x * 64;
  int head = blockIdx.y;
  int kvh = head >> 2;
  int tid = threadIdx.x;
  int lane = tid & 63, wave = tid >> 6;
  int g = lane >> 4, cc = lane & 15;
  int wq0 = wave * 16;

#pragma unroll
  for (int i = 0; i < 4; ++i) {
    int c = tid + i * 256;
    int row = c >> 4, ks = (c & 15) << 3;
    size_t gofs = (size_t)(qs + row) * (NQ * HD) + head * HD + ks;
    *(u16x8*)&Qs[0][row][ks] = *(const u16x8*)(qh + gofs);
    *(u16x8*)&Qs[1][row][ks] = *(const u16x8*)(ql + gofs);
  }
  if (tid < 64) posq[tid] = pos[qs + tid];

  float m_r[4], l_r[4];
  f32x4 acc_o[6];
#pragma unroll
  for (int r = 0; r < 4; ++r) { m_r[r] = -__builtin_huge_valf(); l_r[r] = 0.f; }
#pragma unroll
  for (int n = 0; n < 6; ++n) acc_o[n] = fzero4();

  int kstart = qs - (WIN - 1);
  if (kstart < 0) kstart = 0;
  kstart &= ~31;
  int kend = qs + 63;

  for (int k0 = kstart; k0 <= kend; k0 += 32) {
    __syncthreads();
#pragma unroll
    for (int i = 0; i < 2; ++i) {
      int c = tid + i * 256;
      int row = c >> 4, ks = (c & 15) << 3;
      size_t gofs = (size_t)(k0 + row) * (NKV * HD) + kvh * HD + ks;
      *(u16x8*)&Ks[0][row][ks] = *(const u16x8*)(kh + gofs);
      *(u16x8*)&Ks[1][row][ks] = *(const u16x8*)(kl + gofs);
    }
#pragma unroll
    for (int i = 0; i < 3; ++i) {
      int qd = tid + i * 256;
      int key = qd / 24, vq = qd % 24;
      size_t gofs = (size_t)(k0 + key) * (NKV * VD) + kvh * VD + vq * 4;
      ushort4 a = *(const ushort4*)(vhp + gofs);
      ushort4 b = *(const ushort4*)(vlp + gofs);
      Vt[0][vq * 4 + 0][key] = a.x; Vt[0][vq * 4 + 1][key] = a.y;
      Vt[0][vq * 4 + 2][key] = a.z; Vt[0][vq * 4 + 3][key] = a.w;
      Vt[1][vq * 4 + 0][key] = b.x; Vt[1][vq * 4 + 1][key] = b.y;
      Vt[1][vq * 4 + 2][key] = b.z; Vt[1][vq * 4 + 3][key] = b.w;
    }
    if (tid < 32) posk[tid] = pos[k0 + tid];
    __syncthreads();

    bf16x8 aqh[4], aql[4];
#pragma unroll
    for (int kk = 0; kk < 4; ++kk) {
      aqh[kk] = *(const bf16x8*)&Qs[0][wq0 + cc][kk * 32 + g * 8];
      aql[kk] = *(const bf16x8*)&Qs[1][wq0 + cc][kk * 32 + g * 8];
    }
    f32x4 sacc[2];
    sacc[0] = fzero4(); sacc[1] = fzero4();
#pragma unroll
    for (int kb = 0; kb < 2; ++kb)
#pragma unroll
      for (int kk = 0; kk < 4; ++kk) {
        bf16x8 bh = *(const bf16x8*)&Ks[0][kb * 16 + cc][kk * 32 + g * 8];
        bf16x8 bl = *(const bf16x8*)&Ks[1][kb * 16 + cc][kk * 32 + g * 8];
        sacc[kb] = mfma16(aqh[kk], bh, sacc[kb]);
        sacc[kb] = mfma16(aqh[kk], bl, sacc[kb]);
        sacc[kb] = mfma16(aql[kk], bh, sacc[kb]);
      }

    int j0 = posk[cc], j1 = posk[16 + cc];
#pragma unroll
    for (int r = 0; r < 4; ++r) {
      int irow = posq[wq0 + g * 4 + r];
      float s0 = sacc[0][r] * SCALE;
      float s1 = sacc[1][r] * SCALE;
      bool ok0 = (j0 <= irow) && (irow - j0 < WIN);
      bool ok1 = (j1 <= irow) && (irow - j1 < WIN);
      if (!ok0) s0 = -1e30f;
      if (!ok1) s1 = -1e30f;
      float rm = fmaxf(s0, s1);
#pragma unroll
      for (int off = 1; off < 16; off <<= 1) rm = fmaxf(rm, __shfl_xor(rm, off));
      float mn = fmaxf(m_r[r], rm);
      float p0 = ok0 ? __expf(s0 - mn) : 0.f;
      float p1 = ok1 ? __expf(s1 - mn) : 0.f;
      float rs = p0 + p1;
#pragma unroll
      for (int off = 1; off < 16; off <<= 1) rs += __shfl_xor(rs, off);
      float alpha = __expf(m_r[r] - mn);
      l_r[r] = l_r[r] * alpha + rs;
      m_r[r] = mn;
#pragma unroll
      for (int n = 0; n < 6; ++n) acc_o[n][r] *= alpha;
      unsigned short p0h = f2bf(p0), p1h = f2bf(p1);
      Ps[0][wave][g * 4 + r][cc] = p0h;
      Ps[1][wave][g * 4 + r][cc] = f2bf(p0 - bf2f(p0h));
      Ps[0][wave][g * 4 + r][16 + cc] = p1h;
      Ps[1][wave][g * 4 + r][16 + cc] = f2bf(p1 - bf2f(p1h));
    }
    bf16x8 pah = *(const bf16x8*)&Ps[0][wave][cc][g * 8];
    bf16x8 pal = *(const bf16x8*)&Ps[1][wave][cc][g * 8];
#pragma unroll
    for (int n = 0; n < 6; ++n) {
      bf16x8 bh = *(const bf16x8*)&Vt[0][n * 16 + cc][g * 8];
      bf16x8 bl = *(const bf16x8*)&Vt[1][n * 16 + cc][g * 8];
      acc_o[n] = mfma16(pah, bh, acc_o[n]);
      acc_o[n] = mfma16(pah, bl, acc_o[n]);
      acc_o[n] = mfma16(pal, bh, acc_o[n]);
    }
  }

  float snk = sink[head];
#pragma unroll
  for (int r = 0; r < 4; ++r) {
    float m2 = fmaxf(m_r[r], snk);
    float alpha = __expf(m_r[r] - m2);
    float denom = l_r[r] * alpha + __expf(snk - m2);
    float inv = 1.f / denom;
    int row = qs + wq0 + g * 4 + r;
#pragma unroll
    for (int n = 0; n < 6; ++n) {
      float val = acc_o[n][r] * alpha * inv;
      size_t off = (size_t)row * 9216 + head * VD + n * 16 + cc;
      unsigned short hh = f2bf(val);
      unsigned short lo = f2bf(val - bf2f(hh));
      aocat[off] = hh;
      aocat[off + 3072] = lo;
      aocat[off + 6144] = hh;
    }
  }
}

// ---------------------------------------------------------------------------
__global__ __launch_bounds__(64) void router_kernel(const float* __restrict__ x2,
    const float* __restrict__ gw, float* __restrict__ topkw, int* __restrict__ topkid)
{
  int t = blockIdx.x;
  int lane = threadIdx.x;
  float acc[NE];
#pragma unroll
  for (int e = 0; e < NE; ++e) acc[e] = 0.f;
  for (int hh = lane; hh < H; hh += 64) {
    float xv = x2[(size_t)t * H + hh];
    const float* g = gw + (size_t)hh * NE;
#pragma unroll
    for (int e = 0; e < NE; ++e) acc[e] = fmaf(xv, g[e], acc[e]);
  }
#pragma unroll
  for (int e = 0; e < NE; ++e)
#pragma unroll
    for (int off = 32; off > 0; off >>= 1) acc[e] += __shfl_xor(acc[e], off);
  if (lane == 0) {
    int b1 = 0; float v1 = acc[0];
#pragma unroll
    for (int e = 1; e < NE; ++e) { if (acc[e] > v1) { v1 = acc[e]; b1 = e; } }
    int b2 = -1; float v2 = -3.4e38f;
#pragma unroll
    for (int e = 0; e < NE; ++e) { if (e != b1 && acc[e] > v2) { v2 = acc[e]; b2 = e; } }
    float e2 = __expf(v2 - v1);
    float s = 1.f + e2;
    topkw[t * 2] = 1.f / s;
    topkw[t * 2 + 1] = e2 / s;
    topkid[t * 2] = b1;
    topkid[t * 2 + 1] = b2;
  }
}

__global__ __launch_bounds__(256) void route_build_kernel(
    const int* __restrict__ topkid, int* __restrict__ idssort,
    int* __restrict__ prow, int* __restrict__ eoffs)
{
  __shared__ int cnt[NE];
  __shared__ int off[NE + 1];
  __shared__ int cur[NE];
  int tid = threadIdx.x;
  if (tid < NE) cnt[tid] = 0;
  __syncthreads();
  for (int p = tid; p < T * TOPK; p += 256) atomicAdd(&cnt[topkid[p]], 1);
  __syncthreads();
  if (tid == 0) {
    off[0] = 0;
    for (int e = 0; e < NE; ++e) off[e + 1] = off[e] + cnt[e];
  }
  __syncthreads();
  if (tid < NE) cur[tid] = off[tid];
  __syncthreads();
  for (int p = tid; p < T * TOPK; p += 256) {
    int e = topkid[p];
    int ppos = atomicAdd(&cur[e], 1);
    idssort[ppos] = p >> 1;
    prow[p] = ppos;
  }
  if (tid <= NE) eoffs[tid] = off[tid];
}

// ---------------------------------------------------------------------------
// silu(gate)*up on fused bf16 [4096][2816] (cols 0..1407 gate, 1408.. up).
// ---------------------------------------------------------------------------
__global__ __launch_bounds__(256) void silu_mul_kernel(
    const ushort_t* __restrict__ h12, ushort_t* __restrict__ oh)
{
  int id = blockIdx.x * 256 + threadIdx.x;
  int r = id / 176;
  int c8 = (id % 176) * 8;
  u16x8 a = *(const u16x8*)&h12[(size_t)r * 2816 + c8];
  u16x8 b = *(const u16x8*)&h12[(size_t)r * 2816 + 1408 + c8];
  u16x8 o;
#pragma unroll
  for (int j = 0; j < 8; ++j) {
    float x = bf2f(a[j]), y = bf2f(b[j]);
    float rr = x / (1.f + __expf(-x)) * y;
    o[j] = f2bf(rr);
  }
  *(u16x8*)&oh[(size_t)r * 1408 + c8] = o;
}

__global__ __launch_bounds__(256) void combine_kernel(const float* __restrict__ h,
    const float* __restrict__ eo, const float* __restrict__ topkw,
    const int* __restrict__ prow, float* __restrict__ out)
{
  int t = blockIdx.x, tid = threadIdx.x;
  float w0 = topkw[t * 2], w1 = topkw[t * 2 + 1];
  const float4* e0 = (const float4*)(eo + (size_t)prow[t * 2] * H);
  const float4* e1 = (const float4*)(eo + (size_t)prow[t * 2 + 1] * H);
  const float4* hp = (const float4*)(h + (size_t)t * H);
  float4* op = (float4*)(out + (size_t)t * H);
#pragma unroll
  for (int i = 0; i < 4; ++i) {
    int idx = tid + i * 256;
    float4 a = hp[idx], b = e0[idx], c = e1[idx];
    float4 o;
    o.x = a.x + w0 * b.x + w1 * c.x;
    o.y = a.y + w0 * b.y + w1 * c.y;
    o.z = a.z + w0 * b.z + w1 * c.z;
    o.w = a.w + w0 * b.w + w1 * c.w;
    op[idx] = o;
  }
}

// ---------------------------------------------------------------------------
extern "C" void kernel_launch(void* const* d_in, const int* in_sizes, int n_in,
                              void* d_out, int out_size, void* d_ws, size_t ws_size,
                              hipStream_t stream) {
  const int*   pos   = (const int*)d_in[0];
  const float* hid   = (const float*)d_in[1];
  const float* rms1w = (const float*)d_in[2];
  const float* rms2w = (const float*)d_in[3];
  const float* wq    = (const float*)d_in[4];
  const float* wk    = (const float*)d_in[5];
  const float* wv    = (const float*)d_in[6];
  const float* wo    = (const float*)d_in[7];
  const float* sink  = (const float*)d_in[8];
  const float* gw    = (const float*)d_in[9];
  const float* wgate = (const float*)d_in[10];
  const float* wup   = (const float*)d_in[11];
  const float* wdown = (const float*)d_in[12];
  float* out = (float*)d_out;

  const size_t MB = 1048576ull;
  if (ws_size < 462ull * MB) return;

  char* ws = (char*)d_ws;
  // ---- weight region (phased reuse; NON-OVERLAPPING in phase 1) ----
  ushort_t* wqkvTc = (ushort_t*)(ws + 0 * MB);      // 139 MiB [5888][12288]
  ushort_t* woTc   = (ushort_t*)(ws + 139 * MB);    // 72  MiB [4096][9216]
  ushort_t* wdownT = (ushort_t*)(ws + 211 * MB);    // 88  MiB [8][4096][1408]
  ushort_t* wgupT  = (ushort_t*)(ws + 0 * MB);      // 176 MiB (after QKV+WO dead)
  // ---- activations (A0 = ws+299MB) ----
  char* A0 = ws + 299 * MB;
  float* h     = (float*)(A0 + 0 * MB);             // 32 MiB  (step5 -> step9)
  ushort_t* x1cat = (ushort_t*)(A0 + 32 * MB);      // 48 MiB  (step1 -> step2)
  ushort_t* qh  = (ushort_t*)(A0 + 32 * MB);        // 16 MiB  (step3 -> step4, over x1cat)
  ushort_t* ql  = (ushort_t*)(A0 + 48 * MB);        // 16 MiB
  ushort_t* kh  = (ushort_t*)(A0 + 64 * MB);        // 4 MiB
  ushort_t* kl  = (ushort_t*)(A0 + 68 * MB);        // 4 MiB
  ushort_t* vh  = (ushort_t*)(A0 + 72 * MB);        // 3 MiB
  ushort_t* vl  = (ushort_t*)(A0 + 75 * MB);        // 3 MiB
  float* qkvf  = (float*)(A0 + 80 * MB);            // 46 MiB  (step2 -> step3)
  ushort_t* aocat = (ushort_t*)(A0 + 126 * MB);     // 36 MiB  (step4 -> step5)
  ushort_t* x2h = (ushort_t*)(A0 + 96 * MB);        // 16 MiB  (step6 -> step8)
  float* x2    = (float*)(A0 + 112 * MB);           // 32 MiB  (step6 -> step7)
  ushort_t* h12b = (ushort_t*)(A0 + 112 * MB);      // 22 MiB  (step8, over x2 dead)
  ushort_t* h1h  = (ushort_t*)(A0 + 134 * MB);      // 11 MiB  (step8)
  float* eo    = (float*)(A0 + 32 * MB);            // 64 MiB  (step8 -> step9, over qh..vl dead)
  char* sm = A0 + 162 * MB;
  float* topkw  = (float*)(sm);
  int*  topkid  = (int*)(sm + 16384);
  int*  prow    = (int*)(sm + 32768);
  int*  idssort = (int*)(sm + 49152);
  int*  eoffs   = (int*)(sm + 65536);

  // 0. weight conversion: qkv + wo into K-cat layouts [Bh | Bh | Bl]; down hi-only
  tconv_cat_kernel<<<dim3(64, 64, 1), 256, 0, stream>>>(wq, 4096, wqkvTc, 12288, 0,
      0, 4096, 8192);
  tconv_cat_kernel<<<dim3(16, 64, 1), 256, 0, stream>>>(wk, 1024, wqkvTc, 12288, 4096,
      0, 4096, 8192);
  tconv_cat_kernel<<<dim3(12, 64, 1), 256, 0, stream>>>(wv, 768, wqkvTc, 12288, 5120,
      0, 4096, 8192);
  tconv_cat_kernel<<<dim3(64, 48, 1), 256, 0, stream>>>(wo, 4096, woTc, 9216, 0,
      0, 3072, 6144);
  tconv_kernel<0><<<dim3(64, 22, 8), 256, 0, stream>>>(wdown, 4096, wdownT, nullptr,
      1408, 0, 1408LL * 4096, 4096LL * 1408);

  // 1. x1cat = rmsnorm(hid) -> [hi | lo | hi]
  rmsnorm_cat_kernel<<<T, 256, 0, stream>>>(hid, rms1w, x1cat);

  // 2. fused QKV GEMM (K-cat 3-pass), K=12288
  gemm8p<0, 0, 0, 0><<<dim3(46, 16, 1), 256, 0, stream>>>(
      x1cat, 12288, wqkvTc, 0, qkvf, 5888, nullptr, nullptr, nullptr, T, 12288);

  // 3. RoPE + pack
  rope_pack_kernel<<<T, 256, 0, stream>>>(pos, qkvf, qh, ql, kh, kl, vh, vl);

  // 4. attention -> aocat
  attn_kernel<<<dim3(T / 64, NQ, 1), 256, 0, stream>>>(qh, ql, kh, kl, vh, vl,
      sink, pos, aocat);

  // 5. h = hid + ao @ wo (K-cat 3-pass), K=9216
  gemm8p<0, 0, 0, 1><<<dim3(32, 16, 1), 256, 0, stream>>>(
      aocat, 9216, woTc, 0, h, H, hid, nullptr, nullptr, T, 9216);

  // 6. x2 = rmsnorm(h)
  rmsnorm_fh_kernel<<<T, 256, 0, stream>>>(h, rms2w, x2, x2h);

  // 7. routing
  router_kernel<<<T, 64, 0, stream>>>(x2, gw, topkw, topkid);
  route_build_kernel<<<1, 256, 0, stream>>>(topkid, idssort, prow, eoffs);

  // 8. MoE: convert gate/up weights (reuse dead qkv/wo region), gate+up, silu, down
  tconv_kernel<0><<<dim3(22, 64, 8), 256, 0, stream>>>(wgate, 1408, wgupT, nullptr,
      4096, 0, 4096LL * 1408, 2816LL * 4096);
  tconv_kernel<0><<<dim3(22, 64, 8), 256, 0, stream>>>(wup, 1408, wgupT, nullptr,
      4096, 1408, 4096LL * 1408, 2816LL * 4096);
  gemm8p<1, 1, 1, 0><<<dim3(22, 32, 8), 256, 0, stream>>>(
      x2h, 4096, wgupT, 2816LL * 4096, h12b, 2816, nullptr, idssort, eoffs, 0, 4096);
  silu_mul_kernel<<<2816, 256, 0, stream>>>(h12b, h1h);
  gemm8p<0, 1, 0, 0><<<dim3(32, 32, 8), 256, 0, stream>>>(
      h1h, 1408, wdownT, 4096LL * 1408, eo, H, nullptr, nullptr, eoffs, 0, 1408);

  // 9. out = h + combine(eo)
  combine_kernel<<<T, 256, 0, stream>>>(h, eo, topkw, prow, out);
}

// Round 7
// 1480.168 us; speedup vs baseline: 1.0301x; 1.0301x over previous
//
#include <hip/hip_runtime.h>
#include <math.h>

#define T 2048
#define H 4096
#define NQ 32
#define NKV 8
#define HD 128
#define VD 96
#define WIN 1024
#define NE 8
#define FF 1408
#define TOPK 2

typedef __bf16 bf16x8 __attribute__((ext_vector_type(8)));
typedef unsigned short u16x8 __attribute__((ext_vector_type(8)));
typedef float f32x4 __attribute__((ext_vector_type(4)));
typedef unsigned short ushort_t;

__device__ __forceinline__ unsigned short f2bf(float f) {
  union { float f; unsigned u; } v; v.f = f;
  unsigned r = v.u + 0x7fffu + ((v.u >> 16) & 1u);
  return (unsigned short)(r >> 16);
}
__device__ __forceinline__ float bf2f(unsigned short h) {
  union { unsigned u; float f; } v; v.u = ((unsigned)h) << 16;
  return v.f;
}
__device__ __forceinline__ f32x4 mfma16(bf16x8 a, bf16x8 b, f32x4 c) {
  return __builtin_amdgcn_mfma_f32_16x16x32_bf16(a, b, c, 0, 0, 0);
}
__device__ __forceinline__ f32x4 fzero4() { f32x4 z = {0.f, 0.f, 0.f, 0.f}; return z; }

// async global->LDS 16B copy. Dest must be linear: wave base + lane*16.
__device__ __forceinline__ void gl16(const void* g, void* l) {
  __builtin_amdgcn_global_load_lds(
      (const __attribute__((address_space(1))) void*)g,
      (__attribute__((address_space(3))) void*)l, 16, 0, 0);
}

// ---------------------------------------------------------------------------
// m97-style GEMM: A bf16 [M][K] (pre-split hi/lo), B bf16 BT [N][K].
// global_load_lds staging into linear [128][32] LDS tiles; 128x128 C tile.
// SPLIT: 3-pass compensated. GATHER: A row gather. EOFF: per-expert mode.
// OUTBF: bf16 C. RES: C = acc + res.
// XCD swizzle (T1): bijective chunk remap so each XCD works a contiguous
// B-panel-major region (B-panel L2-resident). Requires nwg % 8 == 0.
// ---------------------------------------------------------------------------
template<int SPLIT, int GATHER, int EOFF, int OUTBF, int RES>
__global__ __launch_bounds__(256) void gemm_bt(
    const ushort_t* __restrict__ Ah, const ushort_t* __restrict__ Al, int lda,
    const ushort_t* __restrict__ Bh, const ushort_t* __restrict__ Bl,
    long long strideBe,
    void* __restrict__ Cp, int ldc,
    const float* __restrict__ res,
    const int* __restrict__ row_idx, const int* __restrict__ e_off,
    int M, int K)
{
  __shared__ __align__(16) ushort_t As[(SPLIT ? 2 : 1) * 4096];
  __shared__ __align__(16) ushort_t Bs[(SPLIT ? 2 : 1) * 4096];

  // XCD-aware block swizzle: chunk-per-XCD, B-panel-major decode.
  int bx = blockIdx.x, by = blockIdx.y;
  {
    int gx = gridDim.x, gy = gridDim.y;
    int nwg = gx * gy;
    if ((nwg & 7) == 0) {
      int id = by * gx + bx;              // original dispatch id -> XCD = id%8
      int cpx = nwg >> 3;
      int id2 = (id & 7) * cpx + (id >> 3);
      bx = id2 / gy;                      // y-fastest within chunk: B reuse
      by = id2 - bx * gy;
    }
  }

  int rowbase = 0, Mloc = M;
  if (EOFF) {
    int e = blockIdx.z;
    rowbase = e_off[e];
    Mloc = e_off[e + 1] - rowbase;
    Bh += strideBe * (long long)e;
    if (SPLIT) Bl += strideBe * (long long)e;
  }
  int mtile = by * 128;
  if (mtile >= Mloc) return;
  int n0 = bx * 128;

  int tid = threadIdx.x;
  int lane = tid & 63, wave = tid >> 6;
  int g = lane >> 4, cc = lane & 15;
  int wrow = (wave >> 1) * 64, wcol = (wave & 1) * 64;

  // staging source pointers (2 x 16B per tile per thread)
  int ks = (tid & 3) << 3;            // k element offset 0/8/16/24
  const ushort_t *aph0, *aph1, *apl0 = nullptr, *apl1 = nullptr;
  {
    int r0 = (tid >> 2), r1 = (tid >> 2) + 64;
    long long ar0, ar1;
    if (EOFF || GATHER) {
      int g0 = mtile + r0; if (g0 >= Mloc) g0 = 0;
      int g1 = mtile + r1; if (g1 >= Mloc) g1 = 0;
      if (GATHER) { ar0 = row_idx[rowbase + g0]; ar1 = row_idx[rowbase + g1]; }
      else { ar0 = rowbase + g0; ar1 = rowbase + g1; }
    } else {
      ar0 = mtile + r0; ar1 = mtile + r1;
    }
    aph0 = Ah + ar0 * lda + ks;
    aph1 = Ah + ar1 * lda + ks;
    if (SPLIT) { apl0 = Al + ar0 * lda + ks; apl1 = Al + ar1 * lda + ks; }
  }
  const ushort_t* bph0 = Bh + (size_t)(n0 + (tid >> 2)) * K + ks;
  const ushort_t* bph1 = Bh + (size_t)(n0 + (tid >> 2) + 64) * K + ks;
  const ushort_t* bpl0 = SPLIT ? Bl + (size_t)(n0 + (tid >> 2)) * K + ks : nullptr;
  const ushort_t* bpl1 = SPLIT ? Bl + (size_t)(n0 + (tid >> 2) + 64) * K + ks : nullptr;
  ushort_t* la0 = As + tid * 8;
  ushort_t* la1 = As + (tid + 256) * 8;
  ushort_t* lb0 = Bs + tid * 8;
  ushort_t* lb1 = Bs + (tid + 256) * 8;

  f32x4 acc[4][4];
#pragma unroll
  for (int m = 0; m < 4; ++m)
#pragma unroll
    for (int n = 0; n < 4; ++n) acc[m][n] = fzero4();

  int nK = K >> 5;
  for (int kt = 0; kt < nK; ++kt) {
    int k0 = kt << 5;
    gl16(aph0 + k0, la0);
    gl16(aph1 + k0, la1);
    gl16(bph0 + k0, lb0);
    gl16(bph1 + k0, lb1);
    if (SPLIT) {
      gl16(apl0 + k0, la0 + 4096);
      gl16(apl1 + k0, la1 + 4096);
      gl16(bpl0 + k0, lb0 + 4096);
      gl16(bpl1 + k0, lb1 + 4096);
    }
    __syncthreads();
    bf16x8 avh[4], bvh[4], avl[4], bvl[4];
#pragma unroll
    for (int m = 0; m < 4; ++m) {
      int row = wrow + m * 16 + cc;
      avh[m] = *(const bf16x8*)&As[row * 32 + g * 8];
      if (SPLIT) avl[m] = *(const bf16x8*)&As[4096 + row * 32 + g * 8];
    }
#pragma unroll
    for (int n = 0; n < 4; ++n) {
      int row = wcol + n * 16 + cc;
      bvh[n] = *(const bf16x8*)&Bs[row * 32 + g * 8];
      if (SPLIT) bvl[n] = *(const bf16x8*)&Bs[4096 + row * 32 + g * 8];
    }
#pragma unroll
    for (int m = 0; m < 4; ++m)
#pragma unroll
      for (int n = 0; n < 4; ++n) {
        acc[m][n] = mfma16(avh[m], bvh[n], acc[m][n]);
        if (SPLIT) {
          acc[m][n] = mfma16(avh[m], bvl[n], acc[m][n]);
          acc[m][n] = mfma16(avl[m], bvh[n], acc[m][n]);
        }
      }
    __syncthreads();
  }

#pragma unroll
  for (int m = 0; m < 4; ++m) {
    int rl = wrow + m * 16 + g * 4;
#pragma unroll
    for (int n = 0; n < 4; ++n) {
      int col = n0 + wcol + n * 16 + cc;
#pragma unroll
      for (int r = 0; r < 4; ++r) {
        int grow = mtile + rl + r;
        if (grow < Mloc) {
          size_t off = (size_t)(rowbase + grow) * ldc + col;
          float vv = acc[m][n][r];
          if (OUTBF) {
            ((ushort_t*)Cp)[off] = f2bf(vv);
          } else {
            if (RES) vv += res[off];
            ((float*)Cp)[off] = vv;
          }
        }
      }
    }
  }
}

// ---------------------------------------------------------------------------
// Transpose + f32->bf16 convert: src [R][C] f32 -> dst BT rows [dro+c][r].
// SPLITOUT=1 also writes the bf16 compensation term to dl.
// ---------------------------------------------------------------------------
template<int SPLITOUT>
__global__ __launch_bounds__(256) void tconv_kernel(
    const float* __restrict__ src, int ldsrc,
    ushort_t* __restrict__ dh, ushort_t* __restrict__ dl,
    int lddst, int dro, long long sE, long long dE)
{
  __shared__ float tile[64][65];
  int e = blockIdx.z;
  src += sE * (long long)e;
  dh += dE * (long long)e;
  if (SPLITOUT) dl += dE * (long long)e;
  int c0 = blockIdx.x * 64;
  int r0 = blockIdx.y * 64;
  int tid = threadIdx.x;
#pragma unroll
  for (int i = 0; i < 4; ++i) {
    int idx = tid + i * 256;
    int r = idx >> 4, c4 = (idx & 15) << 2;
    float4 v = *(const float4*)&src[(size_t)(r0 + r) * ldsrc + c0 + c4];
    tile[r][c4 + 0] = v.x; tile[r][c4 + 1] = v.y;
    tile[r][c4 + 2] = v.z; tile[r][c4 + 3] = v.w;
  }
  __syncthreads();
#pragma unroll
  for (int i = 0; i < 2; ++i) {
    int idx = tid + i * 256;
    int c = idx >> 3, r8 = (idx & 7) << 3;
    u16x8 hv, lv;
#pragma unroll
    for (int j = 0; j < 8; ++j) {
      float f = tile[r8 + j][c];
      unsigned short hh = f2bf(f);
      hv[j] = hh;
      if (SPLITOUT) lv[j] = f2bf(f - bf2f(hh));
    }
    size_t o = (size_t)(dro + c0 + c) * lddst + r0 + r8;
    *(u16x8*)&dh[o] = hv;
    if (SPLITOUT) *(u16x8*)&dl[o] = lv;
  }
}

// ---------------------------------------------------------------------------
// RMSNorm 1: f32 in -> bf16 hi/lo out.
// ---------------------------------------------------------------------------
__global__ __launch_bounds__(256) void rmsnorm_hl_kernel(const float* __restrict__ in,
    const float* __restrict__ w, ushort_t* __restrict__ oh, ushort_t* __restrict__ ol)
{
  int t = blockIdx.x;
  int tid = threadIdx.x;
  const float4* rp = (const float4*)(in + (size_t)t * H);
  const float4* wp = (const float4*)w;
  float4 vv[4];
  float ss = 0.f;
#pragma unroll
  for (int i = 0; i < 4; ++i) {
    vv[i] = rp[tid + i * 256];
    ss += vv[i].x * vv[i].x + vv[i].y * vv[i].y + vv[i].z * vv[i].z + vv[i].w * vv[i].w;
  }
#pragma unroll
  for (int off = 32; off > 0; off >>= 1) ss += __shfl_xor(ss, off);
  __shared__ float red[4];
  if ((tid & 63) == 0) red[tid >> 6] = ss;
  __syncthreads();
  float tot = red[0] + red[1] + red[2] + red[3];
  float rs = rsqrtf(tot * (1.f / H) + 1e-6f);
#pragma unroll
  for (int i = 0; i < 4; ++i) {
    float4 x = vv[i];
    float4 ww = wp[tid + i * 256];
    float y0 = x.x * rs * ww.x, y1 = x.y * rs * ww.y;
    float y2 = x.z * rs * ww.z, y3 = x.w * rs * ww.w;
    ushort4 hh, ll;
    hh.x = f2bf(y0); hh.y = f2bf(y1); hh.z = f2bf(y2); hh.w = f2bf(y3);
    ll.x = f2bf(y0 - bf2f(hh.x)); ll.y = f2bf(y1 - bf2f(hh.y));
    ll.z = f2bf(y2 - bf2f(hh.z)); ll.w = f2bf(y3 - bf2f(hh.w));
    *(ushort4*)&oh[(size_t)t * H + (tid + i * 256) * 4] = hh;
    *(ushort4*)&ol[(size_t)t * H + (tid + i * 256) * 4] = ll;
  }
}

// ---------------------------------------------------------------------------
// RMSNorm 2: f32 in -> f32 out (router) + bf16 hi out (MoE A operand).
// ---------------------------------------------------------------------------
__global__ __launch_bounds__(256) void rmsnorm_fh_kernel(const float* __restrict__ in,
    const float* __restrict__ w, float* __restrict__ of, ushort_t* __restrict__ oh)
{
  int t = blockIdx.x;
  int tid = threadIdx.x;
  const float4* rp = (const float4*)(in + (size_t)t * H);
  const float4* wp = (const float4*)w;
  float4 vv[4];
  float ss = 0.f;
#pragma unroll
  for (int i = 0; i < 4; ++i) {
    vv[i] = rp[tid + i * 256];
    ss += vv[i].x * vv[i].x + vv[i].y * vv[i].y + vv[i].z * vv[i].z + vv[i].w * vv[i].w;
  }
#pragma unroll
  for (int off = 32; off > 0; off >>= 1) ss += __shfl_xor(ss, off);
  __shared__ float red[4];
  if ((tid & 63) == 0) red[tid >> 6] = ss;
  __syncthreads();
  float tot = red[0] + red[1] + red[2] + red[3];
  float rs = rsqrtf(tot * (1.f / H) + 1e-6f);
#pragma unroll
  for (int i = 0; i < 4; ++i) {
    float4 x = vv[i];
    float4 ww = wp[tid + i * 256];
    float4 o;
    o.x = x.x * rs * ww.x; o.y = x.y * rs * ww.y;
    o.z = x.z * rs * ww.z; o.w = x.w * rs * ww.w;
    *(float4*)&of[(size_t)t * H + (tid + i * 256) * 4] = o;
    ushort4 hh;
    hh.x = f2bf(o.x); hh.y = f2bf(o.y); hh.z = f2bf(o.z); hh.w = f2bf(o.w);
    *(ushort4*)&oh[(size_t)t * H + (tid + i * 256) * 4] = hh;
  }
}

// ---------------------------------------------------------------------------
// RoPE + pack from fused qkv f32 [T][5888] -> bf16 hi/lo q/k/v buffers.
// ---------------------------------------------------------------------------
__global__ __launch_bounds__(256) void rope_pack_kernel(const int* __restrict__ pos,
    const float* __restrict__ qkv,
    ushort_t* __restrict__ qh, ushort_t* __restrict__ ql,
    ushort_t* __restrict__ kh, ushort_t* __restrict__ kl,
    ushort_t* __restrict__ vh, ushort_t* __restrict__ vl)
{
  int t = blockIdx.x;
  float p = (float)pos[t];
  int tid = threadIdx.x;
  const float* row = qkv + (size_t)t * 5888;
  for (int idx = tid; idx < (NQ + NKV) * 64; idx += 256) {
    int col; ushort_t *dh, *dl; size_t dbase; int d;
    if (idx < NQ * 64) {
      int hh = idx >> 6; d = idx & 63;
      col = hh * HD + d;
      dbase = (size_t)t * (NQ * HD) + hh * HD;
      dh = qh; dl = ql;
    } else {
      int j = idx - NQ * 64;
      int hh = j >> 6; d = j & 63;
      col = 4096 + hh * HD + d;
      dbase = (size_t)t * (NKV * HD) + hh * HD;
      dh = kh; dl = kl;
    }
    float inv = exp2f(-19.931568569324174f * (float)(2 * d) * (1.0f / 128.0f));
    float ang = p * inv;
    float sn = sinf(ang), cs = cosf(ang);
    float x1 = row[col], x2 = row[col + 64];
    float o1 = x1 * cs - x2 * sn;
    float o2 = x2 * cs + x1 * sn;
    unsigned short h1 = f2bf(o1), h2 = f2bf(o2);
    dh[dbase + d] = h1; dl[dbase + d] = f2bf(o1 - bf2f(h1));
    dh[dbase + d + 64] = h2; dl[dbase + d + 64] = f2bf(o2 - bf2f(h2));
  }
  for (int idx = tid; idx < NKV * VD; idx += 256) {
    float v = row[5120 + idx];
    size_t o = (size_t)t * (NKV * VD) + idx;
    unsigned short hh = f2bf(v);
    vh[o] = hh; vl[o] = f2bf(v - bf2f(hh));
  }
}

// ---------------------------------------------------------------------------
// Flash attention, sliding window + sink; bf16 hi/lo inputs; split-bf16 MFMA.
// XCD swizzle: chunk per XCD = 4 consecutive q-heads (one kv-head) so the
// KV panels (~1.75 MB) stay L2-resident.
// ---------------------------------------------------------------------------
__global__ __launch_bounds__(256) void attn_kernel(
    const ushort_t* __restrict__ qh, const ushort_t* __restrict__ ql,
    const ushort_t* __restrict__ kh, const ushort_t* __restrict__ kl,
    const ushort_t* __restrict__ vhp, const ushort_t* __restrict__ vlp,
    const float* __restrict__ sink, const int* __restrict__ pos,
    ushort_t* __restrict__ aoh, ushort_t* __restrict__ aol)
{
  __shared__ __align__(16) ushort_t Qs[2][64][136];
  __shared__ __align__(16) ushort_t Ks[2][32][136];
  __shared__ __align__(16) ushort_t Vt[2][96][40];
  __shared__ __align__(16) ushort_t Ps[2][4][16][40];
  __shared__ int posq[64];
  __shared__ int posk[32];

  const float SCALE = 0.08838834764831843f;
  int qtile = blockIdx.x, head = blockIdx.y;
  {
    int id = head * 32 + qtile;          // original dispatch id -> XCD = id%8
    int id2 = (id & 7) * 128 + (id >> 3);
    head = id2 >> 5;                     // chunk covers heads [4c, 4c+4)
    qtile = id2 & 31;
  }
  int qs = qtile * 64;
  int kvh = head >> 2;
  int tid = threadIdx.x;
  int lane = tid & 63, wave = tid >> 6;
  int g = lane >> 4, cc = lane & 15;
  int wq0 = wave * 16;

#pragma unroll
  for (int i = 0; i < 4; ++i) {
    int c = tid + i * 256;
    int row = c >> 4, ks = (c & 15) << 3;
    size_t gofs = (size_t)(qs + row) * (NQ * HD) + head * HD + ks;
    *(u16x8*)&Qs[0][row][ks] = *(const u16x8*)(qh + gofs);
    *(u16x8*)&Qs[1][row][ks] = *(const u16x8*)(ql + gofs);
  }
  if (tid < 64) posq[tid] = pos[qs + tid];

  float m_r[4], l_r[4];
  f32x4 acc_o[6];
#pragma unroll
  for (int r = 0; r < 4; ++r) { m_r[r] = -__builtin_huge_valf(); l_r[r] = 0.f; }
#pragma unroll
  for (int n = 0; n < 6; ++n) acc_o[n] = fzero4();

  int kstart = qs - (WIN - 1);
  if (kstart < 0) kstart = 0;
  kstart &= ~31;
  int kend = qs + 63;

  for (int k0 = kstart; k0 <= kend; k0 += 32) {
    __syncthreads();
#pragma unroll
    for (int i = 0; i < 2; ++i) {
      int c = tid + i * 256;
      int row = c >> 4, ks = (c & 15) << 3;
      size_t gofs = (size_t)(k0 + row) * (NKV * HD) + kvh * HD + ks;
      *(u16x8*)&Ks[0][row][ks] = *(const u16x8*)(kh + gofs);
      *(u16x8*)&Ks[1][row][ks] = *(const u16x8*)(kl + gofs);
    }
#pragma unroll
    for (int i = 0; i < 3; ++i) {
      int qd = tid + i * 256;
      int key = qd / 24, vq = qd % 24;
      size_t gofs = (size_t)(k0 + key) * (NKV * VD) + kvh * VD + vq * 4;
      ushort4 a = *(const ushort4*)(vhp + gofs);
      ushort4 b = *(const ushort4*)(vlp + gofs);
      Vt[0][vq * 4 + 0][key] = a.x; Vt[0][vq * 4 + 1][key] = a.y;
      Vt[0][vq * 4 + 2][key] = a.z; Vt[0][vq * 4 + 3][key] = a.w;
      Vt[1][vq * 4 + 0][key] = b.x; Vt[1][vq * 4 + 1][key] = b.y;
      Vt[1][vq * 4 + 2][key] = b.z; Vt[1][vq * 4 + 3][key] = b.w;
    }
    if (tid < 32) posk[tid] = pos[k0 + tid];
    __syncthreads();

    bf16x8 aqh[4], aql[4];
#pragma unroll
    for (int kk = 0; kk < 4; ++kk) {
      aqh[kk] = *(const bf16x8*)&Qs[0][wq0 + cc][kk * 32 + g * 8];
      aql[kk] = *(const bf16x8*)&Qs[1][wq0 + cc][kk * 32 + g * 8];
    }
    f32x4 sacc[2];
    sacc[0] = fzero4(); sacc[1] = fzero4();
#pragma unroll
    for (int kb = 0; kb < 2; ++kb)
#pragma unroll
      for (int kk = 0; kk < 4; ++kk) {
        bf16x8 bh = *(const bf16x8*)&Ks[0][kb * 16 + cc][kk * 32 + g * 8];
        bf16x8 bl = *(const bf16x8*)&Ks[1][kb * 16 + cc][kk * 32 + g * 8];
        sacc[kb] = mfma16(aqh[kk], bh, sacc[kb]);
        sacc[kb] = mfma16(aqh[kk], bl, sacc[kb]);
        sacc[kb] = mfma16(aql[kk], bh, sacc[kb]);
      }

    int j0 = posk[cc], j1 = posk[16 + cc];
#pragma unroll
    for (int r = 0; r < 4; ++r) {
      int irow = posq[wq0 + g * 4 + r];
      float s0 = sacc[0][r] * SCALE;
      float s1 = sacc[1][r] * SCALE;
      bool ok0 = (j0 <= irow) && (irow - j0 < WIN);
      bool ok1 = (j1 <= irow) && (irow - j1 < WIN);
      if (!ok0) s0 = -1e30f;
      if (!ok1) s1 = -1e30f;
      float rm = fmaxf(s0, s1);
#pragma unroll
      for (int off = 1; off < 16; off <<= 1) rm = fmaxf(rm, __shfl_xor(rm, off));
      float mn = fmaxf(m_r[r], rm);
      float p0 = ok0 ? __expf(s0 - mn) : 0.f;
      float p1 = ok1 ? __expf(s1 - mn) : 0.f;
      float rs = p0 + p1;
#pragma unroll
      for (int off = 1; off < 16; off <<= 1) rs += __shfl_xor(rs, off);
      float alpha = __expf(m_r[r] - mn);
      l_r[r] = l_r[r] * alpha + rs;
      m_r[r] = mn;
#pragma unroll
      for (int n = 0; n < 6; ++n) acc_o[n][r] *= alpha;
      unsigned short p0h = f2bf(p0), p1h = f2bf(p1);
      Ps[0][wave][g * 4 + r][cc] = p0h;
      Ps[1][wave][g * 4 + r][cc] = f2bf(p0 - bf2f(p0h));
      Ps[0][wave][g * 4 + r][16 + cc] = p1h;
      Ps[1][wave][g * 4 + r][16 + cc] = f2bf(p1 - bf2f(p1h));
    }
    bf16x8 pah = *(const bf16x8*)&Ps[0][wave][cc][g * 8];
    bf16x8 pal = *(const bf16x8*)&Ps[1][wave][cc][g * 8];
#pragma unroll
    for (int n = 0; n < 6; ++n) {
      bf16x8 bh = *(const bf16x8*)&Vt[0][n * 16 + cc][g * 8];
      bf16x8 bl = *(const bf16x8*)&Vt[1][n * 16 + cc][g * 8];
      acc_o[n] = mfma16(pah, bh, acc_o[n]);
      acc_o[n] = mfma16(pah, bl, acc_o[n]);
      acc_o[n] = mfma16(pal, bh, acc_o[n]);
    }
  }

  float snk = sink[head];
#pragma unroll
  for (int r = 0; r < 4; ++r) {
    float m2 = fmaxf(m_r[r], snk);
    float alpha = __expf(m_r[r] - m2);
    float denom = l_r[r] * alpha + __expf(snk - m2);
    float inv = 1.f / denom;
    int row = qs + wq0 + g * 4 + r;
#pragma unroll
    for (int n = 0; n < 6; ++n) {
      float val = acc_o[n][r] * alpha * inv;
      size_t off = (size_t)row * (NQ * VD) + head * VD + n * 16 + cc;
      unsigned short hh = f2bf(val);
      aoh[off] = hh;
      aol[off] = f2bf(val - bf2f(hh));
    }
  }
}

// ---------------------------------------------------------------------------
__global__ __launch_bounds__(64) void router_kernel(const float* __restrict__ x2,
    const float* __restrict__ gw, float* __restrict__ topkw, int* __restrict__ topkid)
{
  int t = blockIdx.x;
  int lane = threadIdx.x;
  float acc[NE];
#pragma unroll
  for (int e = 0; e < NE; ++e) acc[e] = 0.f;
  for (int hh = lane; hh < H; hh += 64) {
    float xv = x2[(size_t)t * H + hh];
    const float* g = gw + (size_t)hh * NE;
#pragma unroll
    for (int e = 0; e < NE; ++e) acc[e] = fmaf(xv, g[e], acc[e]);
  }
#pragma unroll
  for (int e = 0; e < NE; ++e)
#pragma unroll
    for (int off = 32; off > 0; off >>= 1) acc[e] += __shfl_xor(acc[e], off);
  if (lane == 0) {
    int b1 = 0; float v1 = acc[0];
#pragma unroll
    for (int e = 1; e < NE; ++e) { if (acc[e] > v1) { v1 = acc[e]; b1 = e; } }
    int b2 = -1; float v2 = -3.4e38f;
#pragma unroll
    for (int e = 0; e < NE; ++e) { if (e != b1 && acc[e] > v2) { v2 = acc[e]; b2 = e; } }
    float e2 = __expf(v2 - v1);
    float s = 1.f + e2;
    topkw[t * 2] = 1.f / s;
    topkw[t * 2 + 1] = e2 / s;
    topkid[t * 2] = b1;
    topkid[t * 2 + 1] = b2;
  }
}

__global__ __launch_bounds__(256) void route_build_kernel(
    const int* __restrict__ topkid, int* __restrict__ idssort,
    int* __restrict__ prow, int* __restrict__ eoffs)
{
  __shared__ int cnt[NE];
  __shared__ int off[NE + 1];
  __shared__ int cur[NE];
  int tid = threadIdx.x;
  if (tid < NE) cnt[tid] = 0;
  __syncthreads();
  for (int p = tid; p < T * TOPK; p += 256) atomicAdd(&cnt[topkid[p]], 1);
  __syncthreads();
  if (tid == 0) {
    off[0] = 0;
    for (int e = 0; e < NE; ++e) off[e + 1] = off[e] + cnt[e];
  }
  __syncthreads();
  if (tid < NE) cur[tid] = off[tid];
  __syncthreads();
  for (int p = tid; p < T * TOPK; p += 256) {
    int e = topkid[p];
    int ppos = atomicAdd(&cur[e], 1);
    idssort[ppos] = p >> 1;
    prow[p] = ppos;
  }
  if (tid <= NE) eoffs[tid] = off[tid];
}

// ---------------------------------------------------------------------------
// silu(gate)*up on fused bf16 [4096][2816] (cols 0..1407 gate, 1408.. up).
// ---------------------------------------------------------------------------
__global__ __launch_bounds__(256) void silu_mul_kernel(
    const ushort_t* __restrict__ h12, ushort_t* __restrict__ oh)
{
  int id = blockIdx.x * 256 + threadIdx.x;
  int r = id / 176;
  int c8 = (id % 176) * 8;
  u16x8 a = *(const u16x8*)&h12[(size_t)r * 2816 + c8];
  u16x8 b = *(const u16x8*)&h12[(size_t)r * 2816 + 1408 + c8];
  u16x8 o;
#pragma unroll
  for (int j = 0; j < 8; ++j) {
    float x = bf2f(a[j]), y = bf2f(b[j]);
    float rr = x / (1.f + __expf(-x)) * y;
    o[j] = f2bf(rr);
  }
  *(u16x8*)&oh[(size_t)r * 1408 + c8] = o;
}

__global__ __launch_bounds__(256) void combine_kernel(const float* __restrict__ h,
    const float* __restrict__ eo, const float* __restrict__ topkw,
    const int* __restrict__ prow, float* __restrict__ out)
{
  int t = blockIdx.x, tid = threadIdx.x;
  float w0 = topkw[t * 2], w1 = topkw[t * 2 + 1];
  const float4* e0 = (const float4*)(eo + (size_t)prow[t * 2] * H);
  const float4* e1 = (const float4*)(eo + (size_t)prow[t * 2 + 1] * H);
  const float4* hp = (const float4*)(h + (size_t)t * H);
  float4* op = (float4*)(out + (size_t)t * H);
#pragma unroll
  for (int i = 0; i < 4; ++i) {
    int idx = tid + i * 256;
    float4 a = hp[idx], b = e0[idx], c = e1[idx];
    float4 o;
    o.x = a.x + w0 * b.x + w1 * c.x;
    o.y = a.y + w0 * b.y + w1 * c.y;
    o.z = a.z + w0 * b.z + w1 * c.z;
    o.w = a.w + w0 * b.w + w1 * c.w;
    op[idx] = o;
  }
}

// ---------------------------------------------------------------------------
extern "C" void kernel_launch(void* const* d_in, const int* in_sizes, int n_in,
                              void* d_out, int out_size, void* d_ws, size_t ws_size,
                              hipStream_t stream) {
  const int*   pos   = (const int*)d_in[0];
  const float* hid   = (const float*)d_in[1];
  const float* rms1w = (const float*)d_in[2];
  const float* rms2w = (const float*)d_in[3];
  const float* wq    = (const float*)d_in[4];
  const float* wk    = (const float*)d_in[5];
  const float* wv    = (const float*)d_in[6];
  const float* wo    = (const float*)d_in[7];
  const float* sink  = (const float*)d_in[8];
  const float* gw    = (const float*)d_in[9];
  const float* wgate = (const float*)d_in[10];
  const float* wup   = (const float*)d_in[11];
  const float* wdown = (const float*)d_in[12];
  float* out = (float*)d_out;

  const size_t MB = 1048576ull;
  if (ws_size < 462ull * MB) return;  // visible clean fail if scratch too small

  char* ws = (char*)d_ws;
  // ---- weight region (phased reuse) ----
  ushort_t* wqkvT_h = (ushort_t*)(ws + 0 * MB);     // 46 MiB [5888][4096]
  ushort_t* wqkvT_l = (ushort_t*)(ws + 47 * MB);    // 46 MiB
  ushort_t* woT_h   = (ushort_t*)(ws + 94 * MB);    // 24 MiB [4096][3072]
  ushort_t* woT_l   = (ushort_t*)(ws + 118 * MB);   // 24 MiB
  ushort_t* wgupT   = (ushort_t*)(ws + 0 * MB);     // 176 MiB [8][2816][4096] (after WO)
  ushort_t* wdownT  = (ushort_t*)(ws + 176 * MB);   // 88 MiB [8][4096][1408]
  // ---- activations ----
  char* A0 = ws + 264 * MB;
  ushort_t* x1h = (ushort_t*)(A0 + 0 * MB);
  ushort_t* x1l = (ushort_t*)(A0 + 16 * MB);
  ushort_t* kh  = (ushort_t*)(A0 + 32 * MB);
  ushort_t* kl  = (ushort_t*)(A0 + 36 * MB);
  ushort_t* vh  = (ushort_t*)(A0 + 40 * MB);
  ushort_t* vl  = (ushort_t*)(A0 + 43 * MB);
  ushort_t* aoh = (ushort_t*)(A0 + 46 * MB);
  ushort_t* aol = (ushort_t*)(A0 + 58 * MB);
  ushort_t* qh  = (ushort_t*)(A0 + 0 * MB);         // over x1h (dead after QKV)
  ushort_t* ql  = (ushort_t*)(A0 + 16 * MB);        // over x1l
  float* eo   = (float*)(A0 + 0 * MB);              // 64 MiB over q/k/v/ao (dead)
  float* qkvf = (float*)(A0 + 70 * MB);             // 46 MiB [2048][5888]
  ushort_t* h12b = (ushort_t*)(A0 + 70 * MB);       // 22 MiB over qkvf (dead)
  ushort_t* h1h  = (ushort_t*)(A0 + 93 * MB);       // 11 MiB
  float* h   = (float*)(A0 + 116 * MB);
  float* x2  = (float*)(A0 + 148 * MB);
  ushort_t* x2h = (ushort_t*)(A0 + 180 * MB);
  char* sm = A0 + 196 * MB;
  float* topkw  = (float*)(sm);
  int*  topkid  = (int*)(sm + 16384);
  int*  prow    = (int*)(sm + 32768);
  int*  idssort = (int*)(sm + 49152);
  int*  eoffs   = (int*)(sm + 65536);

  // 0. weight conversion (qkv fused + wo split hi/lo; down hi only)
  tconv_kernel<1><<<dim3(64, 64, 1), 256, 0, stream>>>(wq, 4096, wqkvT_h, wqkvT_l, 4096, 0, 0, 0);
  tconv_kernel<1><<<dim3(16, 64, 1), 256, 0, stream>>>(wk, 1024, wqkvT_h, wqkvT_l, 4096, 4096, 0, 0);
  tconv_kernel<1><<<dim3(12, 64, 1), 256, 0, stream>>>(wv, 768, wqkvT_h, wqkvT_l, 4096, 5120, 0, 0);
  tconv_kernel<1><<<dim3(64, 48, 1), 256, 0, stream>>>(wo, 4096, woT_h, woT_l, 3072, 0, 0, 0);
  tconv_kernel<0><<<dim3(64, 22, 8), 256, 0, stream>>>(wdown, 4096, wdownT, nullptr,
      1408, 0, 1408LL * 4096, 4096LL * 1408);

  // 1. x1 = rmsnorm(hid) -> bf16 hi/lo
  rmsnorm_hl_kernel<<<T, 256, 0, stream>>>(hid, rms1w, x1h, x1l);

  // 2. fused QKV GEMM (split)
  gemm_bt<1, 0, 0, 0, 0><<<dim3(46, 16, 1), 256, 0, stream>>>(
      x1h, x1l, H, wqkvT_h, wqkvT_l, 0, qkvf, 5888, nullptr, nullptr, nullptr, T, H);

  // 3. RoPE + pack
  rope_pack_kernel<<<T, 256, 0, stream>>>(pos, qkvf, qh, ql, kh, kl, vh, vl);

  // 4. attention
  attn_kernel<<<dim3(T / 64, NQ, 1), 256, 0, stream>>>(qh, ql, kh, kl, vh, vl,
      sink, pos, aoh, aol);

  // 5. h = hid + ao @ wo (split)
  gemm_bt<1, 0, 0, 0, 1><<<dim3(32, 16, 1), 256, 0, stream>>>(
      aoh, aol, NQ * VD, woT_h, woT_l, 0, h, H, hid, nullptr, nullptr, T, NQ * VD);

  // 6. x2 = rmsnorm(h)
  rmsnorm_fh_kernel<<<T, 256, 0, stream>>>(h, rms2w, x2, x2h);

  // 7. routing
  router_kernel<<<T, 64, 0, stream>>>(x2, gw, topkw, topkid);
  route_build_kernel<<<1, 256, 0, stream>>>(topkid, idssort, prow, eoffs);

  // 8. MoE weight conversion (reuses dead qkv/wo weight region), gate+up, silu, down
  tconv_kernel<0><<<dim3(22, 64, 8), 256, 0, stream>>>(wgate, 1408, wgupT, nullptr, 4096, 0,
      4096LL * 1408, 2816LL * 4096);
  tconv_kernel<0><<<dim3(22, 64, 8), 256, 0, stream>>>(wup, 1408, wgupT, nullptr, 4096, 1408,
      4096LL * 1408, 2816LL * 4096);
  gemm_bt<0, 1, 1, 1, 0><<<dim3(22, 32, 8), 256, 0, stream>>>(
      x2h, nullptr, H, wgupT, nullptr, 2816LL * 4096, h12b, 2816, nullptr, idssort, eoffs, 0, H);
  silu_mul_kernel<<<2816, 256, 0, stream>>>(h12b, h1h);
  gemm_bt<0, 0, 1, 0, 0><<<dim3(32, 32, 8), 256, 0, stream>>>(
      h1h, nullptr, FF, wdownT, nullptr, 4096LL * 1408, eo, H, nullptr, nullptr, eoffs, 0, FF);

  // 9. out = h + combine(eo)
  combine_kernel<<<T, 256, 0, stream>>>(h, eo, topkw, prow, out);
}

// Round 8
// 1356.647 us; speedup vs baseline: 1.1239x; 1.0910x over previous
//
#include <hip/hip_runtime.h>
#include <math.h>

#define T 2048
#define H 4096
#define NQ 32
#define NKV 8
#define HD 128
#define VD 96
#define WIN 1024
#define NE 8
#define FF 1408
#define TOPK 2

typedef __bf16 bf16x8 __attribute__((ext_vector_type(8)));
typedef unsigned short u16x8 __attribute__((ext_vector_type(8)));
typedef float f32x4 __attribute__((ext_vector_type(4)));
typedef unsigned short ushort_t;

__device__ __forceinline__ unsigned short f2bf(float f) {
  union { float f; unsigned u; } v; v.f = f;
  unsigned r = v.u + 0x7fffu + ((v.u >> 16) & 1u);
  return (unsigned short)(r >> 16);
}
__device__ __forceinline__ float bf2f(unsigned short h) {
  union { unsigned u; float f; } v; v.u = ((unsigned)h) << 16;
  return v.f;
}
__device__ __forceinline__ f32x4 mfma16(bf16x8 a, bf16x8 b, f32x4 c) {
  return __builtin_amdgcn_mfma_f32_16x16x32_bf16(a, b, c, 0, 0, 0);
}
__device__ __forceinline__ f32x4 fzero4() { f32x4 z = {0.f, 0.f, 0.f, 0.f}; return z; }

// async global->LDS 16B copy. Dest must be linear: wave base + lane*16.
__device__ __forceinline__ void gl16(const void* g, void* l) {
  __builtin_amdgcn_global_load_lds(
      (const __attribute__((address_space(1))) void*)g,
      (__attribute__((address_space(3))) void*)l, 16, 0, 0);
}

// ---------------------------------------------------------------------------
// m97-style GEMM: A bf16 [M][K] (pre-split hi/lo), B bf16 BT [N][K].
// global_load_lds staging into linear [128][32] LDS tiles; 128x128 C tile.
// SPLIT: 3-pass compensated. GATHER: A row gather. EOFF: per-expert mode.
// OUTBF: bf16 C. RES: C = acc + res.
// XCD swizzle (T1): bijective chunk remap, B-panel-major decode.
// ---------------------------------------------------------------------------
template<int SPLIT, int GATHER, int EOFF, int OUTBF, int RES>
__global__ __launch_bounds__(256) void gemm_bt(
    const ushort_t* __restrict__ Ah, const ushort_t* __restrict__ Al, int lda,
    const ushort_t* __restrict__ Bh, const ushort_t* __restrict__ Bl,
    long long strideBe,
    void* __restrict__ Cp, int ldc,
    const float* __restrict__ res,
    const int* __restrict__ row_idx, const int* __restrict__ e_off,
    int M, int K)
{
  __shared__ __align__(16) ushort_t As[(SPLIT ? 2 : 1) * 4096];
  __shared__ __align__(16) ushort_t Bs[(SPLIT ? 2 : 1) * 4096];

  int bx = blockIdx.x, by = blockIdx.y;
  {
    int gx = gridDim.x, gy = gridDim.y;
    int nwg = gx * gy;
    if ((nwg & 7) == 0) {
      int id = by * gx + bx;
      int cpx = nwg >> 3;
      int id2 = (id & 7) * cpx + (id >> 3);
      bx = id2 / gy;
      by = id2 - bx * gy;
    }
  }

  int rowbase = 0, Mloc = M;
  if (EOFF) {
    int e = blockIdx.z;
    rowbase = e_off[e];
    Mloc = e_off[e + 1] - rowbase;
    Bh += strideBe * (long long)e;
    if (SPLIT) Bl += strideBe * (long long)e;
  }
  int mtile = by * 128;
  if (mtile >= Mloc) return;
  int n0 = bx * 128;

  int tid = threadIdx.x;
  int lane = tid & 63, wave = tid >> 6;
  int g = lane >> 4, cc = lane & 15;
  int wrow = (wave >> 1) * 64, wcol = (wave & 1) * 64;

  int ks = (tid & 3) << 3;
  const ushort_t *aph0, *aph1, *apl0 = nullptr, *apl1 = nullptr;
  {
    int r0 = (tid >> 2), r1 = (tid >> 2) + 64;
    long long ar0, ar1;
    if (EOFF || GATHER) {
      int g0 = mtile + r0; if (g0 >= Mloc) g0 = 0;
      int g1 = mtile + r1; if (g1 >= Mloc) g1 = 0;
      if (GATHER) { ar0 = row_idx[rowbase + g0]; ar1 = row_idx[rowbase + g1]; }
      else { ar0 = rowbase + g0; ar1 = rowbase + g1; }
    } else {
      ar0 = mtile + r0; ar1 = mtile + r1;
    }
    aph0 = Ah + ar0 * lda + ks;
    aph1 = Ah + ar1 * lda + ks;
    if (SPLIT) { apl0 = Al + ar0 * lda + ks; apl1 = Al + ar1 * lda + ks; }
  }
  const ushort_t* bph0 = Bh + (size_t)(n0 + (tid >> 2)) * K + ks;
  const ushort_t* bph1 = Bh + (size_t)(n0 + (tid >> 2) + 64) * K + ks;
  const ushort_t* bpl0 = SPLIT ? Bl + (size_t)(n0 + (tid >> 2)) * K + ks : nullptr;
  const ushort_t* bpl1 = SPLIT ? Bl + (size_t)(n0 + (tid >> 2) + 64) * K + ks : nullptr;
  ushort_t* la0 = As + tid * 8;
  ushort_t* la1 = As + (tid + 256) * 8;
  ushort_t* lb0 = Bs + tid * 8;
  ushort_t* lb1 = Bs + (tid + 256) * 8;

  f32x4 acc[4][4];
#pragma unroll
  for (int m = 0; m < 4; ++m)
#pragma unroll
    for (int n = 0; n < 4; ++n) acc[m][n] = fzero4();

  int nK = K >> 5;
  for (int kt = 0; kt < nK; ++kt) {
    int k0 = kt << 5;
    gl16(aph0 + k0, la0);
    gl16(aph1 + k0, la1);
    gl16(bph0 + k0, lb0);
    gl16(bph1 + k0, lb1);
    if (SPLIT) {
      gl16(apl0 + k0, la0 + 4096);
      gl16(apl1 + k0, la1 + 4096);
      gl16(bpl0 + k0, lb0 + 4096);
      gl16(bpl1 + k0, lb1 + 4096);
    }
    __syncthreads();
    bf16x8 avh[4], bvh[4], avl[4], bvl[4];
#pragma unroll
    for (int m = 0; m < 4; ++m) {
      int row = wrow + m * 16 + cc;
      avh[m] = *(const bf16x8*)&As[row * 32 + g * 8];
      if (SPLIT) avl[m] = *(const bf16x8*)&As[4096 + row * 32 + g * 8];
    }
#pragma unroll
    for (int n = 0; n < 4; ++n) {
      int row = wcol + n * 16 + cc;
      bvh[n] = *(const bf16x8*)&Bs[row * 32 + g * 8];
      if (SPLIT) bvl[n] = *(const bf16x8*)&Bs[4096 + row * 32 + g * 8];
    }
#pragma unroll
    for (int m = 0; m < 4; ++m)
#pragma unroll
      for (int n = 0; n < 4; ++n) {
        acc[m][n] = mfma16(avh[m], bvh[n], acc[m][n]);
        if (SPLIT) {
          acc[m][n] = mfma16(avh[m], bvl[n], acc[m][n]);
          acc[m][n] = mfma16(avl[m], bvh[n], acc[m][n]);
        }
      }
    __syncthreads();
  }

#pragma unroll
  for (int m = 0; m < 4; ++m) {
    int rl = wrow + m * 16 + g * 4;
#pragma unroll
    for (int n = 0; n < 4; ++n) {
      int col = n0 + wcol + n * 16 + cc;
#pragma unroll
      for (int r = 0; r < 4; ++r) {
        int grow = mtile + rl + r;
        if (grow < Mloc) {
          size_t off = (size_t)(rowbase + grow) * ldc + col;
          float vv = acc[m][n][r];
          if (OUTBF) {
            ((ushort_t*)Cp)[off] = f2bf(vv);
          } else {
            if (RES) vv += res[off];
            ((float*)Cp)[off] = vv;
          }
        }
      }
    }
  }
}

// ---------------------------------------------------------------------------
// Transpose + f32->bf16 convert: src [R][C] f32 -> dst BT rows [dro+c][r].
// ---------------------------------------------------------------------------
template<int SPLITOUT>
__global__ __launch_bounds__(256) void tconv_kernel(
    const float* __restrict__ src, int ldsrc,
    ushort_t* __restrict__ dh, ushort_t* __restrict__ dl,
    int lddst, int dro, long long sE, long long dE)
{
  __shared__ float tile[64][65];
  int e = blockIdx.z;
  src += sE * (long long)e;
  dh += dE * (long long)e;
  if (SPLITOUT) dl += dE * (long long)e;
  int c0 = blockIdx.x * 64;
  int r0 = blockIdx.y * 64;
  int tid = threadIdx.x;
#pragma unroll
  for (int i = 0; i < 4; ++i) {
    int idx = tid + i * 256;
    int r = idx >> 4, c4 = (idx & 15) << 2;
    float4 v = *(const float4*)&src[(size_t)(r0 + r) * ldsrc + c0 + c4];
    tile[r][c4 + 0] = v.x; tile[r][c4 + 1] = v.y;
    tile[r][c4 + 2] = v.z; tile[r][c4 + 3] = v.w;
  }
  __syncthreads();
#pragma unroll
  for (int i = 0; i < 2; ++i) {
    int idx = tid + i * 256;
    int c = idx >> 3, r8 = (idx & 7) << 3;
    u16x8 hv, lv;
#pragma unroll
    for (int j = 0; j < 8; ++j) {
      float f = tile[r8 + j][c];
      unsigned short hh = f2bf(f);
      hv[j] = hh;
      if (SPLITOUT) lv[j] = f2bf(f - bf2f(hh));
    }
    size_t o = (size_t)(dro + c0 + c) * lddst + r0 + r8;
    *(u16x8*)&dh[o] = hv;
    if (SPLITOUT) *(u16x8*)&dl[o] = lv;
  }
}

// ---------------------------------------------------------------------------
// V transpose: qkvf [T][5888] f32 (cols 5120+) -> vtT hi/lo [NKV][VD][T] bf16.
// 32x32 tiles; coalesced both sides.
// ---------------------------------------------------------------------------
__global__ __launch_bounds__(256) void vtrans_kernel(const float* __restrict__ qkv,
    ushort_t* __restrict__ vth, ushort_t* __restrict__ vtl)
{
  __shared__ float tile[32][33];
  int t0 = blockIdx.x * 32;
  int vd0 = blockIdx.y * 32;
  int kvh = blockIdx.z;
  int tid = threadIdx.x;
  {
    int tr = tid >> 3, c4 = (tid & 7) << 2;
    float4 v = *(const float4*)&qkv[(size_t)(t0 + tr) * 5888 + 5120 + kvh * VD + vd0 + c4];
    tile[tr][c4 + 0] = v.x; tile[tr][c4 + 1] = v.y;
    tile[tr][c4 + 2] = v.z; tile[tr][c4 + 3] = v.w;
  }
  __syncthreads();
  {
    int vd = tid >> 3, t4 = (tid & 7) << 2;
    ushort4 hh, ll;
    float f0 = tile[t4 + 0][vd], f1 = tile[t4 + 1][vd];
    float f2 = tile[t4 + 2][vd], f3 = tile[t4 + 3][vd];
    hh.x = f2bf(f0); ll.x = f2bf(f0 - bf2f(hh.x));
    hh.y = f2bf(f1); ll.y = f2bf(f1 - bf2f(hh.y));
    hh.z = f2bf(f2); ll.z = f2bf(f2 - bf2f(hh.z));
    hh.w = f2bf(f3); ll.w = f2bf(f3 - bf2f(hh.w));
    size_t o = (size_t)kvh * (VD * T) + (size_t)(vd0 + vd) * T + t0 + t4;
    *(ushort4*)&vth[o] = hh;
    *(ushort4*)&vtl[o] = ll;
  }
}

// ---------------------------------------------------------------------------
// RMSNorm 1: f32 in -> bf16 hi/lo out.
// ---------------------------------------------------------------------------
__global__ __launch_bounds__(256) void rmsnorm_hl_kernel(const float* __restrict__ in,
    const float* __restrict__ w, ushort_t* __restrict__ oh, ushort_t* __restrict__ ol)
{
  int t = blockIdx.x;
  int tid = threadIdx.x;
  const float4* rp = (const float4*)(in + (size_t)t * H);
  const float4* wp = (const float4*)w;
  float4 vv[4];
  float ss = 0.f;
#pragma unroll
  for (int i = 0; i < 4; ++i) {
    vv[i] = rp[tid + i * 256];
    ss += vv[i].x * vv[i].x + vv[i].y * vv[i].y + vv[i].z * vv[i].z + vv[i].w * vv[i].w;
  }
#pragma unroll
  for (int off = 32; off > 0; off >>= 1) ss += __shfl_xor(ss, off);
  __shared__ float red[4];
  if ((tid & 63) == 0) red[tid >> 6] = ss;
  __syncthreads();
  float tot = red[0] + red[1] + red[2] + red[3];
  float rs = rsqrtf(tot * (1.f / H) + 1e-6f);
#pragma unroll
  for (int i = 0; i < 4; ++i) {
    float4 x = vv[i];
    float4 ww = wp[tid + i * 256];
    float y0 = x.x * rs * ww.x, y1 = x.y * rs * ww.y;
    float y2 = x.z * rs * ww.z, y3 = x.w * rs * ww.w;
    ushort4 hh, ll;
    hh.x = f2bf(y0); hh.y = f2bf(y1); hh.z = f2bf(y2); hh.w = f2bf(y3);
    ll.x = f2bf(y0 - bf2f(hh.x)); ll.y = f2bf(y1 - bf2f(hh.y));
    ll.z = f2bf(y2 - bf2f(hh.z)); ll.w = f2bf(y3 - bf2f(hh.w));
    *(ushort4*)&oh[(size_t)t * H + (tid + i * 256) * 4] = hh;
    *(ushort4*)&ol[(size_t)t * H + (tid + i * 256) * 4] = ll;
  }
}

// ---------------------------------------------------------------------------
// RMSNorm 2: f32 in -> f32 out (router) + bf16 hi out (MoE A operand).
// ---------------------------------------------------------------------------
__global__ __launch_bounds__(256) void rmsnorm_fh_kernel(const float* __restrict__ in,
    const float* __restrict__ w, float* __restrict__ of, ushort_t* __restrict__ oh)
{
  int t = blockIdx.x;
  int tid = threadIdx.x;
  const float4* rp = (const float4*)(in + (size_t)t * H);
  const float4* wp = (const float4*)w;
  float4 vv[4];
  float ss = 0.f;
#pragma unroll
  for (int i = 0; i < 4; ++i) {
    vv[i] = rp[tid + i * 256];
    ss += vv[i].x * vv[i].x + vv[i].y * vv[i].y + vv[i].z * vv[i].z + vv[i].w * vv[i].w;
  }
#pragma unroll
  for (int off = 32; off > 0; off >>= 1) ss += __shfl_xor(ss, off);
  __shared__ float red[4];
  if ((tid & 63) == 0) red[tid >> 6] = ss;
  __syncthreads();
  float tot = red[0] + red[1] + red[2] + red[3];
  float rs = rsqrtf(tot * (1.f / H) + 1e-6f);
#pragma unroll
  for (int i = 0; i < 4; ++i) {
    float4 x = vv[i];
    float4 ww = wp[tid + i * 256];
    float4 o;
    o.x = x.x * rs * ww.x; o.y = x.y * rs * ww.y;
    o.z = x.z * rs * ww.z; o.w = x.w * rs * ww.w;
    *(float4*)&of[(size_t)t * H + (tid + i * 256) * 4] = o;
    ushort4 hh;
    hh.x = f2bf(o.x); hh.y = f2bf(o.y); hh.z = f2bf(o.z); hh.w = f2bf(o.w);
    *(ushort4*)&oh[(size_t)t * H + (tid + i * 256) * 4] = hh;
  }
}

// ---------------------------------------------------------------------------
// RoPE + pack q/k only (V handled by vtrans).
// ---------------------------------------------------------------------------
__global__ __launch_bounds__(256) void rope_pack_kernel(const int* __restrict__ pos,
    const float* __restrict__ qkv,
    ushort_t* __restrict__ qh, ushort_t* __restrict__ ql,
    ushort_t* __restrict__ kh, ushort_t* __restrict__ kl)
{
  int t = blockIdx.x;
  float p = (float)pos[t];
  int tid = threadIdx.x;
  const float* row = qkv + (size_t)t * 5888;
  for (int idx = tid; idx < (NQ + NKV) * 64; idx += 256) {
    int col; ushort_t *dh, *dl; size_t dbase; int d;
    if (idx < NQ * 64) {
      int hh = idx >> 6; d = idx & 63;
      col = hh * HD + d;
      dbase = (size_t)t * (NQ * HD) + hh * HD;
      dh = qh; dl = ql;
    } else {
      int j = idx - NQ * 64;
      int hh = j >> 6; d = j & 63;
      col = 4096 + hh * HD + d;
      dbase = (size_t)t * (NKV * HD) + hh * HD;
      dh = kh; dl = kl;
    }
    float inv = exp2f(-19.931568569324174f * (float)(2 * d) * (1.0f / 128.0f));
    float ang = p * inv;
    float sn = sinf(ang), cs = cosf(ang);
    float x1 = row[col], x2 = row[col + 64];
    float o1 = x1 * cs - x2 * sn;
    float o2 = x2 * cs + x1 * sn;
    unsigned short h1 = f2bf(o1), h2 = f2bf(o2);
    dh[dbase + d] = h1; dl[dbase + d] = f2bf(o1 - bf2f(h1));
    dh[dbase + d + 64] = h2; dl[dbase + d + 64] = f2bf(o2 - bf2f(h2));
  }
}

// ---------------------------------------------------------------------------
// Flash attention, sliding window + sink; split-bf16 MFMA.
// Q fragments in registers (loaded once); V^T staged from precomputed global
// V^T with conflict-free vectorized LDS ops. XCD swizzle: 4 q-heads/chunk.
// ---------------------------------------------------------------------------
__global__ __launch_bounds__(256) void attn_kernel(
    const ushort_t* __restrict__ qh, const ushort_t* __restrict__ ql,
    const ushort_t* __restrict__ kh, const ushort_t* __restrict__ kl,
    const ushort_t* __restrict__ vth, const ushort_t* __restrict__ vtl,
    const float* __restrict__ sink, const int* __restrict__ pos,
    ushort_t* __restrict__ aoh, ushort_t* __restrict__ aol)
{
  __shared__ __align__(16) ushort_t Ks[2][32][136];
  __shared__ __align__(16) ushort_t Vt[2][96][40];
  __shared__ __align__(16) ushort_t Ps[2][4][16][40];
  __shared__ int posq[64];
  __shared__ int posk[32];

  const float SCALE = 0.08838834764831843f;
  int qtile = blockIdx.x, head = blockIdx.y;
  {
    int id = head * 32 + qtile;
    int id2 = (id & 7) * 128 + (id >> 3);
    head = id2 >> 5;
    qtile = id2 & 31;
  }
  int qs = qtile * 64;
  int kvh = head >> 2;
  int tid = threadIdx.x;
  int lane = tid & 63, wave = tid >> 6;
  int g = lane >> 4, cc = lane & 15;
  int wq0 = wave * 16;
  size_t vbase = (size_t)kvh * (VD * T);

  // Q fragments in registers (loop-invariant)
  bf16x8 aqh[4], aql[4];
  {
    size_t qoff = (size_t)(qs + wq0 + cc) * (NQ * HD) + head * HD + g * 8;
#pragma unroll
    for (int kk = 0; kk < 4; ++kk) {
      aqh[kk] = *(const bf16x8*)(qh + qoff + kk * 32);
      aql[kk] = *(const bf16x8*)(ql + qoff + kk * 32);
    }
  }
  if (tid < 64) posq[tid] = pos[qs + tid];

  float m_r[4], l_r[4];
  f32x4 acc_o[6];
#pragma unroll
  for (int r = 0; r < 4; ++r) { m_r[r] = -__builtin_huge_valf(); l_r[r] = 0.f; }
#pragma unroll
  for (int n = 0; n < 6; ++n) acc_o[n] = fzero4();

  int kstart = qs - (WIN - 1);
  if (kstart < 0) kstart = 0;
  kstart &= ~31;
  int kend = qs + 63;

  for (int k0 = kstart; k0 <= kend; k0 += 32) {
    __syncthreads();
    // K tile: coalesced u16x8, conflict-free LDS writes
#pragma unroll
    for (int i = 0; i < 2; ++i) {
      int c = tid + i * 256;
      int row = c >> 4, ks = (c & 15) << 3;
      size_t gofs = (size_t)(k0 + row) * (NKV * HD) + kvh * HD + ks;
      *(u16x8*)&Ks[0][row][ks] = *(const u16x8*)(kh + gofs);
      *(u16x8*)&Ks[1][row][ks] = *(const u16x8*)(kl + gofs);
    }
    // V^T tile: 96 vd x 32 keys, hi+lo = 768 u16x8 chunks
#pragma unroll
    for (int i = 0; i < 3; ++i) {
      int id = tid + i * 256;           // 0..767
      int plane = id >> 9;              // wrong for 384 split; use compare
      plane = (id >= 384) ? 1 : 0;
      int r = id - plane * 384;
      int vd = r >> 2, kc = (r & 3) << 3;
      const ushort_t* src = (plane ? vtl : vth) + vbase + (size_t)vd * T + k0 + kc;
      *(u16x8*)&Vt[plane][vd][kc] = *(const u16x8*)src;
    }
    if (tid < 32) posk[tid] = pos[k0 + tid];
    __syncthreads();

    f32x4 sacc[2];
    sacc[0] = fzero4(); sacc[1] = fzero4();
#pragma unroll
    for (int kb = 0; kb < 2; ++kb)
#pragma unroll
      for (int kk = 0; kk < 4; ++kk) {
        bf16x8 bh = *(const bf16x8*)&Ks[0][kb * 16 + cc][kk * 32 + g * 8];
        bf16x8 bl = *(const bf16x8*)&Ks[1][kb * 16 + cc][kk * 32 + g * 8];
        sacc[kb] = mfma16(aqh[kk], bh, sacc[kb]);
        sacc[kb] = mfma16(aqh[kk], bl, sacc[kb]);
        sacc[kb] = mfma16(aql[kk], bh, sacc[kb]);
      }

    int j0 = posk[cc], j1 = posk[16 + cc];
#pragma unroll
    for (int r = 0; r < 4; ++r) {
      int irow = posq[wq0 + g * 4 + r];
      float s0 = sacc[0][r] * SCALE;
      float s1 = sacc[1][r] * SCALE;
      bool ok0 = (j0 <= irow) && (irow - j0 < WIN);
      bool ok1 = (j1 <= irow) && (irow - j1 < WIN);
      if (!ok0) s0 = -1e30f;
      if (!ok1) s1 = -1e30f;
      float rm = fmaxf(s0, s1);
#pragma unroll
      for (int off = 1; off < 16; off <<= 1) rm = fmaxf(rm, __shfl_xor(rm, off));
      float mn = fmaxf(m_r[r], rm);
      float p0 = ok0 ? __expf(s0 - mn) : 0.f;
      float p1 = ok1 ? __expf(s1 - mn) : 0.f;
      float rs = p0 + p1;
#pragma unroll
      for (int off = 1; off < 16; off <<= 1) rs += __shfl_xor(rs, off);
      float alpha = __expf(m_r[r] - mn);
      l_r[r] = l_r[r] * alpha + rs;
      m_r[r] = mn;
#pragma unroll
      for (int n = 0; n < 6; ++n) acc_o[n][r] *= alpha;
      unsigned short p0h = f2bf(p0), p1h = f2bf(p1);
      Ps[0][wave][g * 4 + r][cc] = p0h;
      Ps[1][wave][g * 4 + r][cc] = f2bf(p0 - bf2f(p0h));
      Ps[0][wave][g * 4 + r][16 + cc] = p1h;
      Ps[1][wave][g * 4 + r][16 + cc] = f2bf(p1 - bf2f(p1h));
    }
    bf16x8 pah = *(const bf16x8*)&Ps[0][wave][cc][g * 8];
    bf16x8 pal = *(const bf16x8*)&Ps[1][wave][cc][g * 8];
#pragma unroll
    for (int n = 0; n < 6; ++n) {
      bf16x8 bh = *(const bf16x8*)&Vt[0][n * 16 + cc][g * 8];
      bf16x8 bl = *(const bf16x8*)&Vt[1][n * 16 + cc][g * 8];
      acc_o[n] = mfma16(pah, bh, acc_o[n]);
      acc_o[n] = mfma16(pah, bl, acc_o[n]);
      acc_o[n] = mfma16(pal, bh, acc_o[n]);
    }
  }

  float snk = sink[head];
#pragma unroll
  for (int r = 0; r < 4; ++r) {
    float m2 = fmaxf(m_r[r], snk);
    float alpha = __expf(m_r[r] - m2);
    float denom = l_r[r] * alpha + __expf(snk - m2);
    float inv = 1.f / denom;
    int row = qs + wq0 + g * 4 + r;
#pragma unroll
    for (int n = 0; n < 6; ++n) {
      float val = acc_o[n][r] * alpha * inv;
      size_t off = (size_t)row * (NQ * VD) + head * VD + n * 16 + cc;
      unsigned short hh = f2bf(val);
      aoh[off] = hh;
      aol[off] = f2bf(val - bf2f(hh));
    }
  }
}

// ---------------------------------------------------------------------------
__global__ __launch_bounds__(64) void router_kernel(const float* __restrict__ x2,
    const float* __restrict__ gw, float* __restrict__ topkw, int* __restrict__ topkid)
{
  int t = blockIdx.x;
  int lane = threadIdx.x;
  float acc[NE];
#pragma unroll
  for (int e = 0; e < NE; ++e) acc[e] = 0.f;
  for (int hh = lane; hh < H; hh += 64) {
    float xv = x2[(size_t)t * H + hh];
    const float* g = gw + (size_t)hh * NE;
#pragma unroll
    for (int e = 0; e < NE; ++e) acc[e] = fmaf(xv, g[e], acc[e]);
  }
#pragma unroll
  for (int e = 0; e < NE; ++e)
#pragma unroll
    for (int off = 32; off > 0; off >>= 1) acc[e] += __shfl_xor(acc[e], off);
  if (lane == 0) {
    int b1 = 0; float v1 = acc[0];
#pragma unroll
    for (int e = 1; e < NE; ++e) { if (acc[e] > v1) { v1 = acc[e]; b1 = e; } }
    int b2 = -1; float v2 = -3.4e38f;
#pragma unroll
    for (int e = 0; e < NE; ++e) { if (e != b1 && acc[e] > v2) { v2 = acc[e]; b2 = e; } }
    float e2 = __expf(v2 - v1);
    float s = 1.f + e2;
    topkw[t * 2] = 1.f / s;
    topkw[t * 2 + 1] = e2 / s;
    topkid[t * 2] = b1;
    topkid[t * 2 + 1] = b2;
  }
}

__global__ __launch_bounds__(256) void route_build_kernel(
    const int* __restrict__ topkid, int* __restrict__ idssort,
    int* __restrict__ prow, int* __restrict__ eoffs)
{
  __shared__ int cnt[NE];
  __shared__ int off[NE + 1];
  __shared__ int cur[NE];
  int tid = threadIdx.x;
  if (tid < NE) cnt[tid] = 0;
  __syncthreads();
  for (int p = tid; p < T * TOPK; p += 256) atomicAdd(&cnt[topkid[p]], 1);
  __syncthreads();
  if (tid == 0) {
    off[0] = 0;
    for (int e = 0; e < NE; ++e) off[e + 1] = off[e] + cnt[e];
  }
  __syncthreads();
  if (tid < NE) cur[tid] = off[tid];
  __syncthreads();
  for (int p = tid; p < T * TOPK; p += 256) {
    int e = topkid[p];
    int ppos = atomicAdd(&cur[e], 1);
    idssort[ppos] = p >> 1;
    prow[p] = ppos;
  }
  if (tid <= NE) eoffs[tid] = off[tid];
}

// ---------------------------------------------------------------------------
// silu(gate)*up on fused bf16 [4096][2816] (cols 0..1407 gate, 1408.. up).
// ---------------------------------------------------------------------------
__global__ __launch_bounds__(256) void silu_mul_kernel(
    const ushort_t* __restrict__ h12, ushort_t* __restrict__ oh)
{
  int id = blockIdx.x * 256 + threadIdx.x;
  int r = id / 176;
  int c8 = (id % 176) * 8;
  u16x8 a = *(const u16x8*)&h12[(size_t)r * 2816 + c8];
  u16x8 b = *(const u16x8*)&h12[(size_t)r * 2816 + 1408 + c8];
  u16x8 o;
#pragma unroll
  for (int j = 0; j < 8; ++j) {
    float x = bf2f(a[j]), y = bf2f(b[j]);
    float rr = x / (1.f + __expf(-x)) * y;
    o[j] = f2bf(rr);
  }
  *(u16x8*)&oh[(size_t)r * 1408 + c8] = o;
}

__global__ __launch_bounds__(256) void combine_kernel(const float* __restrict__ h,
    const float* __restrict__ eo, const float* __restrict__ topkw,
    const int* __restrict__ prow, float* __restrict__ out)
{
  int t = blockIdx.x, tid = threadIdx.x;
  float w0 = topkw[t * 2], w1 = topkw[t * 2 + 1];
  const float4* e0 = (const float4*)(eo + (size_t)prow[t * 2] * H);
  const float4* e1 = (const float4*)(eo + (size_t)prow[t * 2 + 1] * H);
  const float4* hp = (const float4*)(h + (size_t)t * H);
  float4* op = (float4*)(out + (size_t)t * H);
#pragma unroll
  for (int i = 0; i < 4; ++i) {
    int idx = tid + i * 256;
    float4 a = hp[idx], b = e0[idx], c = e1[idx];
    float4 o;
    o.x = a.x + w0 * b.x + w1 * c.x;
    o.y = a.y + w0 * b.y + w1 * c.y;
    o.z = a.z + w0 * b.z + w1 * c.z;
    o.w = a.w + w0 * b.w + w1 * c.w;
    op[idx] = o;
  }
}

// ---------------------------------------------------------------------------
extern "C" void kernel_launch(void* const* d_in, const int* in_sizes, int n_in,
                              void* d_out, int out_size, void* d_ws, size_t ws_size,
                              hipStream_t stream) {
  const int*   pos   = (const int*)d_in[0];
  const float* hid   = (const float*)d_in[1];
  const float* rms1w = (const float*)d_in[2];
  const float* rms2w = (const float*)d_in[3];
  const float* wq    = (const float*)d_in[4];
  const float* wk    = (const float*)d_in[5];
  const float* wv    = (const float*)d_in[6];
  const float* wo    = (const float*)d_in[7];
  const float* sink  = (const float*)d_in[8];
  const float* gw    = (const float*)d_in[9];
  const float* wgate = (const float*)d_in[10];
  const float* wup   = (const float*)d_in[11];
  const float* wdown = (const float*)d_in[12];
  float* out = (float*)d_out;

  const size_t MB = 1048576ull;
  if (ws_size < 462ull * MB) return;  // visible clean fail if scratch too small

  char* ws = (char*)d_ws;
  // ---- weight region (phased reuse) ----
  ushort_t* wqkvT_h = (ushort_t*)(ws + 0 * MB);     // 46 MiB [5888][4096]
  ushort_t* wqkvT_l = (ushort_t*)(ws + 47 * MB);    // 46 MiB
  ushort_t* woT_h   = (ushort_t*)(ws + 94 * MB);    // 24 MiB [4096][3072]
  ushort_t* woT_l   = (ushort_t*)(ws + 118 * MB);   // 24 MiB
  ushort_t* wgupT   = (ushort_t*)(ws + 0 * MB);     // 176 MiB [8][2816][4096] (after WO)
  ushort_t* wdownT  = (ushort_t*)(ws + 176 * MB);   // 88 MiB [8][4096][1408]
  // ---- activations ----
  char* A0 = ws + 264 * MB;
  ushort_t* x1h = (ushort_t*)(A0 + 0 * MB);
  ushort_t* x1l = (ushort_t*)(A0 + 16 * MB);
  ushort_t* kh  = (ushort_t*)(A0 + 32 * MB);
  ushort_t* kl  = (ushort_t*)(A0 + 36 * MB);
  ushort_t* vtTh = (ushort_t*)(A0 + 40 * MB);       // 3 MiB [8][96][2048]
  ushort_t* vtTl = (ushort_t*)(A0 + 43 * MB);       // 3 MiB
  ushort_t* aoh = (ushort_t*)(A0 + 46 * MB);
  ushort_t* aol = (ushort_t*)(A0 + 58 * MB);
  ushort_t* qh  = (ushort_t*)(A0 + 0 * MB);         // over x1h (dead after QKV)
  ushort_t* ql  = (ushort_t*)(A0 + 16 * MB);        // over x1l
  float* eo   = (float*)(A0 + 0 * MB);              // 64 MiB over q/k/v/ao (dead)
  float* qkvf = (float*)(A0 + 70 * MB);             // 46 MiB [2048][5888]
  ushort_t* h12b = (ushort_t*)(A0 + 70 * MB);       // 22 MiB over qkvf (dead)
  ushort_t* h1h  = (ushort_t*)(A0 + 93 * MB);       // 11 MiB
  float* h   = (float*)(A0 + 116 * MB);
  float* x2  = (float*)(A0 + 148 * MB);
  ushort_t* x2h = (ushort_t*)(A0 + 180 * MB);
  char* sm = A0 + 196 * MB;
  float* topkw  = (float*)(sm);
  int*  topkid  = (int*)(sm + 16384);
  int*  prow    = (int*)(sm + 32768);
  int*  idssort = (int*)(sm + 49152);
  int*  eoffs   = (int*)(sm + 65536);

  // 0. weight conversion (qkv fused + wo split hi/lo; down hi only)
  tconv_kernel<1><<<dim3(64, 64, 1), 256, 0, stream>>>(wq, 4096, wqkvT_h, wqkvT_l, 4096, 0, 0, 0);
  tconv_kernel<1><<<dim3(16, 64, 1), 256, 0, stream>>>(wk, 1024, wqkvT_h, wqkvT_l, 4096, 4096, 0, 0);
  tconv_kernel<1><<<dim3(12, 64, 1), 256, 0, stream>>>(wv, 768, wqkvT_h, wqkvT_l, 4096, 5120, 0, 0);
  tconv_kernel<1><<<dim3(64, 48, 1), 256, 0, stream>>>(wo, 4096, woT_h, woT_l, 3072, 0, 0, 0);
  tconv_kernel<0><<<dim3(64, 22, 8), 256, 0, stream>>>(wdown, 4096, wdownT, nullptr,
      1408, 0, 1408LL * 4096, 4096LL * 1408);

  // 1. x1 = rmsnorm(hid) -> bf16 hi/lo
  rmsnorm_hl_kernel<<<T, 256, 0, stream>>>(hid, rms1w, x1h, x1l);

  // 2. fused QKV GEMM (split)
  gemm_bt<1, 0, 0, 0, 0><<<dim3(46, 16, 1), 256, 0, stream>>>(
      x1h, x1l, H, wqkvT_h, wqkvT_l, 0, qkvf, 5888, nullptr, nullptr, nullptr, T, H);

  // 3. RoPE + pack q/k; V^T transpose
  rope_pack_kernel<<<T, 256, 0, stream>>>(pos, qkvf, qh, ql, kh, kl);
  vtrans_kernel<<<dim3(64, 3, 8), 256, 0, stream>>>(qkvf, vtTh, vtTl);

  // 4. attention
  attn_kernel<<<dim3(T / 64, NQ, 1), 256, 0, stream>>>(qh, ql, kh, kl, vtTh, vtTl,
      sink, pos, aoh, aol);

  // 5. h = hid + ao @ wo (split)
  gemm_bt<1, 0, 0, 0, 1><<<dim3(32, 16, 1), 256, 0, stream>>>(
      aoh, aol, NQ * VD, woT_h, woT_l, 0, h, H, hid, nullptr, nullptr, T, NQ * VD);

  // 6. x2 = rmsnorm(h)
  rmsnorm_fh_kernel<<<T, 256, 0, stream>>>(h, rms2w, x2, x2h);

  // 7. routing
  router_kernel<<<T, 64, 0, stream>>>(x2, gw, topkw, topkid);
  route_build_kernel<<<1, 256, 0, stream>>>(topkid, idssort, prow, eoffs);

  // 8. MoE weight conversion (reuses dead qkv/wo weight region), gate+up, silu, down
  tconv_kernel<0><<<dim3(22, 64, 8), 256, 0, stream>>>(wgate, 1408, wgupT, nullptr, 4096, 0,
      4096LL * 1408, 2816LL * 4096);
  tconv_kernel<0><<<dim3(22, 64, 8), 256, 0, stream>>>(wup, 1408, wgupT, nullptr, 4096, 1408,
      4096LL * 1408, 2816LL * 4096);
  gemm_bt<0, 1, 1, 1, 0><<<dim3(22, 32, 8), 256, 0, stream>>>(
      x2h, nullptr, H, wgupT, nullptr, 2816LL * 4096, h12b, 2816, nullptr, idssort, eoffs, 0, H);
  silu_mul_kernel<<<2816, 256, 0, stream>>>(h12b, h1h);
  gemm_bt<0, 0, 1, 0, 0><<<dim3(32, 32, 8), 256, 0, stream>>>(
      h1h, nullptr, FF, wdownT, nullptr, 4096LL * 1408, eo, H, nullptr, nullptr, eoffs, 0, FF);

  // 9. out = h + combine(eo)
  combine_kernel<<<T, 256, 0, stream>>>(h, eo, topkw, prow, out);
}